// Round 1
// baseline (6128.493 us; speedup 1.0000x reference)
//
#include <hip/hip_runtime.h>
#include <hip/hip_bf16.h>
#include <math.h>

#define B_  4
#define C_  64
#define H_  192
#define W_  192
#define HW  36864           // H_*W_
#define CHW 2359296         // C_*HW

__device__ __forceinline__ float leakyf(float v) { return v >= 0.f ? v : 0.1f * v; }
__device__ __forceinline__ float sigmoidf_(float v) { return 1.f / (1.f + __expf(-v)); }

// ---------------------------------------------------------------------------
// K0: transpose w_dc (o,c,k) -> (k,c,o) for coalesced LDS staging in deform
// ---------------------------------------------------------------------------
__global__ void k_wdc_t(const float* __restrict__ w, float* __restrict__ wt) {
    int i = blockIdx.x * 256 + threadIdx.x;   // 64*64*9 = 36864
    if (i < 64 * 64 * 9) {
        int k = i % 9;
        int c = (i / 9) % 64;
        int o = i / (9 * 64);
        wt[(k * 64 + c) * 64 + o] = w[i];
    }
}

// ---------------------------------------------------------------------------
// K1: offset/mask conv: 3x3, 64 -> 27, pad 1, leaky; ch>=18 additionally sigmoid
// block = 192 threads (one row), grid = (192 rows, 27 oc, 4 b)
// ---------------------------------------------------------------------------
__global__ __launch_bounds__(192) void k_conv_off(const float* __restrict__ x,
                                                  const float* __restrict__ w,
                                                  const float* __restrict__ bias,
                                                  float* __restrict__ om) {
    int xc = threadIdx.x;      // 0..191
    int y  = blockIdx.x;       // 0..191
    int o  = blockIdx.y;       // 0..26
    int b  = blockIdx.z;
    const float* xb = x + (size_t)b * CHW;
    const float* wo = w + (size_t)o * C_ * 9;
    float acc = bias[o];
    for (int c = 0; c < C_; ++c) {
        const float* xcp = xb + c * HW;
        const float* wc  = wo + c * 9;
        #pragma unroll
        for (int dy = -1; dy <= 1; ++dy) {
            int yy = y + dy;
            if (yy < 0 || yy >= H_) continue;
            const float* row = xcp + yy * W_;
            #pragma unroll
            for (int dx = -1; dx <= 1; ++dx) {
                int xx = xc + dx;
                float v = (xx >= 0 && xx < W_) ? row[xx] : 0.f;
                acc += v * wc[(dy + 1) * 3 + (dx + 1)];
            }
        }
    }
    acc = leakyf(acc);
    if (o >= 18) acc = sigmoidf_(acc);
    om[((size_t)b * 27 + o) * HW + y * W_ + xc] = acc;
}

// ---------------------------------------------------------------------------
// K2: deformable conv. 256 threads, tile = 32 pixels, all 64 oc per block.
// grid = (HW/32 = 1152, B)
// ---------------------------------------------------------------------------
__global__ __launch_bounds__(256) void k_deform(const float* __restrict__ x,
                                                const float* __restrict__ om,
                                                const float* __restrict__ wt,   // (k,c,o)
                                                const float* __restrict__ bias,
                                                float* __restrict__ xd) {
    __shared__ float w_k[64 * 64];      // [c][o] for current k
    __shared__ float val[32 * 65];      // [p][c], padded stride 65
    __shared__ int   sidx[4][32];
    __shared__ float swgt[4][32];

    int t  = threadIdx.x;
    int p  = t & 31;
    int og = t >> 5;                    // 0..7 -> o = og*8 + i
    int b  = blockIdx.y;
    int pix = blockIdx.x * 32 + p;      // < HW
    int py_i = pix / W_;
    int px_i = pix - py_i * W_;

    float acc[8];
    #pragma unroll
    for (int i = 0; i < 8; ++i) acc[i] = bias[og * 8 + i];

    const float* xb  = x  + (size_t)b * CHW;
    const float* omb = om + (size_t)b * 27 * HW;

    for (int k = 0; k < 9; ++k) {
        __syncthreads();    // protect LDS from previous iteration's readers
        // stage w for this k: (c,o) layout, coalesced
        #pragma unroll
        for (int i = 0; i < 16; ++i) {
            int e = t + i * 256;
            w_k[e] = wt[k * 4096 + e];
        }
        // bilinear params for the 32 pixels
        if (t < 32) {
            float offy = omb[(size_t)(2 * k)     * HW + pix];
            float offx = omb[(size_t)(2 * k + 1) * HW + pix];
            float m    = omb[(size_t)(18 + k)    * HW + pix];
            float py = (float)py_i + (float)(k / 3 - 1) + offy;
            float px = (float)px_i + (float)(k % 3 - 1) + offx;
            float y0f = floorf(py), x0f = floorf(px);
            float wy = py - y0f, wx = px - x0f;
            int y0 = (int)y0f, x0 = (int)x0f;
            #pragma unroll
            for (int j = 0; j < 4; ++j) {
                int yy = y0 + (j >> 1);
                int xx = x0 + (j & 1);
                bool v = (yy >= 0) && (yy < H_) && (xx >= 0) && (xx < W_);
                int yc = min(max(yy, 0), H_ - 1);
                int xcl = min(max(xx, 0), W_ - 1);
                sidx[j][p] = yc * W_ + xcl;
                float wj = ((j >> 1) ? wy : 1.f - wy) * ((j & 1) ? wx : 1.f - wx);
                swgt[j][p] = v ? wj * m : 0.f;
            }
        }
        __syncthreads();
        // sampled values: 64c x 32p entries, 8 per thread
        #pragma unroll
        for (int i = 0; i < 8; ++i) {
            int e  = t + i * 256;
            int c  = e >> 5;
            int pp = e & 31;
            const float* xcp = xb + c * HW;
            float v = xcp[sidx[0][pp]] * swgt[0][pp]
                    + xcp[sidx[1][pp]] * swgt[1][pp]
                    + xcp[sidx[2][pp]] * swgt[2][pp]
                    + xcp[sidx[3][pp]] * swgt[3][pp];
            val[pp * 65 + c] = v;
        }
        __syncthreads();
        // MAC: 64 c x 8 o per thread
        for (int c = 0; c < 64; ++c) {
            float v = val[p * 65 + c];
            #pragma unroll
            for (int i = 0; i < 8; ++i)
                acc[i] += v * w_k[c * 64 + og * 8 + i];
        }
    }
    #pragma unroll
    for (int i = 0; i < 8; ++i)
        xd[(size_t)b * CHW + (size_t)(og * 8 + i) * HW + pix] = acc[i];
}

// ---------------------------------------------------------------------------
// K3a: per-(b,c) spatial mean of xd
// ---------------------------------------------------------------------------
__global__ __launch_bounds__(256) void k_camean(const float* __restrict__ xd,
                                                float* __restrict__ ca_in) {
    int bc = blockIdx.x;     // 0..255
    const float* ptr = xd + (size_t)bc * HW;
    float s = 0.f;
    for (int i = threadIdx.x; i < HW; i += 256) s += ptr[i];
    __shared__ float sm[256];
    sm[threadIdx.x] = s;
    __syncthreads();
    for (int st = 128; st > 0; st >>= 1) {
        if (threadIdx.x < st) sm[threadIdx.x] += sm[threadIdx.x + st];
        __syncthreads();
    }
    if (threadIdx.x == 0) ca_in[bc] = sm[0] * (1.f / (float)HW);
}

// ---------------------------------------------------------------------------
// K3b: tiny MLP 64->8 (relu) ->64 (sigmoid), all 4 batches, one block
// ---------------------------------------------------------------------------
__global__ __launch_bounds__(256) void k_ca_mlp(const float* __restrict__ ca_in,
                                                const float* __restrict__ w1,
                                                const float* __restrict__ b1,
                                                const float* __restrict__ w2,
                                                const float* __restrict__ b2,
                                                float* __restrict__ ca_out) {
    __shared__ float h[32];
    int t = threadIdx.x;
    if (t < 32) {
        int b = t >> 3, j = t & 7;
        float a = b1[j];
        for (int c = 0; c < 64; ++c) a += w1[j * 64 + c] * ca_in[b * 64 + c];
        h[t] = a > 0.f ? a : 0.f;
    }
    __syncthreads();
    int b = t >> 6, c = t & 63;
    float a = b2[c];
    #pragma unroll
    for (int j = 0; j < 8; ++j) a += w2[c * 8 + j] * h[b * 8 + j];
    ca_out[t] = sigmoidf_(a);
}

// ---------------------------------------------------------------------------
// K4: spatial attention: 3x3 conv 64->1 + sigmoid. Row blocks.
// ---------------------------------------------------------------------------
__global__ __launch_bounds__(192) void k_sa(const float* __restrict__ xd,
                                            const float* __restrict__ w,
                                            const float* __restrict__ bias,
                                            float* __restrict__ sa) {
    int xc = threadIdx.x;
    int y  = blockIdx.x;
    int b  = blockIdx.z;
    const float* xb = xd + (size_t)b * CHW;
    float acc = bias[0];
    for (int c = 0; c < C_; ++c) {
        const float* xcp = xb + c * HW;
        const float* wc  = w + c * 9;
        #pragma unroll
        for (int dy = -1; dy <= 1; ++dy) {
            int yy = y + dy;
            if (yy < 0 || yy >= H_) continue;
            const float* row = xcp + yy * W_;
            #pragma unroll
            for (int dx = -1; dx <= 1; ++dx) {
                int xx = xc + dx;
                float v = (xx >= 0 && xx < W_) ? row[xx] : 0.f;
                acc += v * wc[(dy + 1) * 3 + (dx + 1)];
            }
        }
    }
    sa[(size_t)b * HW + y * W_ + xc] = sigmoidf_(acc);
}

// ---------------------------------------------------------------------------
// K5: xa = xd * (ca + sa), in place on xd
// ---------------------------------------------------------------------------
__global__ __launch_bounds__(256) void k_scale(float* __restrict__ xd,
                                               const float* __restrict__ ca,
                                               const float* __restrict__ sa) {
    long i = (long)blockIdx.x * 256 + threadIdx.x;  // < B_*CHW
    int b = (int)(i / CHW);
    int r = (int)(i - (long)b * CHW);
    int c = r / HW;
    int p = r - c * HW;
    xd[i] *= (ca[b * 64 + c] + sa[(size_t)b * HW + p]);
}

// ---------------------------------------------------------------------------
// K6/K8: 1x1 conv, 64 in-ch, optional leaky. oc is block-uniform -> scalar w.
// grid = (144 p-chunks, out_ch, 4)
// ---------------------------------------------------------------------------
__global__ __launch_bounds__(256) void k_conv1x1(const float* __restrict__ in,
                                                 const float* __restrict__ w,
                                                 const float* __restrict__ bias,
                                                 float* __restrict__ out,
                                                 int oc_base, int do_leaky) {
    int p  = blockIdx.x * 256 + threadIdx.x;   // < HW
    int oc = blockIdx.y;
    int nc = gridDim.y;
    int b  = blockIdx.z;
    int go = oc_base + oc;
    const float* xb = in + (size_t)b * CHW + p;
    const float* wo = w + (size_t)go * 64;
    float acc = bias[go];
    #pragma unroll 8
    for (int c = 0; c < 64; ++c) acc += xb[(size_t)c * HW] * wo[c];
    if (do_leaky) acc = leakyf(acc);
    out[((size_t)b * nc + oc) * HW + p] = acc;
}

// ---------------------------------------------------------------------------
// K7: 3x3 conv over a 64-ch chunk, accumulate into xr (=d_out).
// chunk 0 initializes with bias. Row blocks, oc block-uniform -> scalar w.
// ---------------------------------------------------------------------------
__global__ __launch_bounds__(192) void k_conv3x3_acc(const float* __restrict__ t,
                                                     const float* __restrict__ w,
                                                     const float* __restrict__ bias,
                                                     float* __restrict__ xr,
                                                     int chunk) {
    int xc = threadIdx.x;
    int y  = blockIdx.x;
    int oc = blockIdx.y;
    int b  = blockIdx.z;
    const float* tb = t + (size_t)b * CHW;
    const float* wo = w + ((size_t)oc * 256 + (size_t)chunk * 64) * 9;
    size_t oidx = ((size_t)b * 64 + oc) * HW + y * W_ + xc;
    float acc = (chunk == 0) ? bias[oc] : xr[oidx];
    for (int c = 0; c < 64; ++c) {
        const float* tc = tb + c * HW;
        const float* wc = wo + c * 9;
        #pragma unroll
        for (int dy = -1; dy <= 1; ++dy) {
            int yy = y + dy;
            if (yy < 0 || yy >= H_) continue;
            const float* row = tc + yy * W_;
            #pragma unroll
            for (int dx = -1; dx <= 1; ++dx) {
                int xx = xc + dx;
                float v = (xx >= 0 && xx < W_) ? row[xx] : 0.f;
                acc += v * wc[(dy + 1) * 3 + (dx + 1)];
            }
        }
    }
    xr[oidx] = acc;
}

// ---------------------------------------------------------------------------
// K9: depthwise 3x3, 32 channels. Row blocks.
// ---------------------------------------------------------------------------
__global__ __launch_bounds__(192) void k_dw3x3(const float* __restrict__ t1,
                                               const float* __restrict__ w,
                                               const float* __restrict__ bias,
                                               float* __restrict__ t2) {
    int xc = threadIdx.x;
    int y  = blockIdx.x;
    int c  = blockIdx.y;
    int b  = blockIdx.z;
    const float* src = t1 + ((size_t)b * 32 + c) * HW;
    const float* wc  = w + c * 9;
    float acc = bias[c];
    #pragma unroll
    for (int dy = -1; dy <= 1; ++dy) {
        int yy = y + dy;
        if (yy < 0 || yy >= H_) continue;
        const float* row = src + yy * W_;
        #pragma unroll
        for (int dx = -1; dx <= 1; ++dx) {
            int xx = xc + dx;
            float v = (xx >= 0 && xx < W_) ? row[xx] : 0.f;
            acc += v * wc[(dy + 1) * 3 + (dx + 1)];
        }
    }
    t2[((size_t)b * 32 + c) * HW + y * W_ + xc] = acc;
}

// ---------------------------------------------------------------------------
// K10: out = x + xr(in d_out) + (w_n3 @ t2 + b_n3)
// ---------------------------------------------------------------------------
__global__ __launch_bounds__(256) void k_final(const float* __restrict__ x,
                                               const float* __restrict__ t2,
                                               const float* __restrict__ w,
                                               const float* __restrict__ bias,
                                               float* __restrict__ out) {
    int p  = blockIdx.x * 256 + threadIdx.x;
    int oc = blockIdx.y;
    int b  = blockIdx.z;
    const float* tb = t2 + (size_t)b * 32 * HW + p;
    const float* wo = w + oc * 32;
    float acc = bias[oc];
    #pragma unroll 8
    for (int c = 0; c < 32; ++c) acc += tb[(size_t)c * HW] * wo[c];
    size_t idx = ((size_t)b * 64 + oc) * HW + p;
    out[idx] = x[idx] + out[idx] + acc;
}

// ---------------------------------------------------------------------------
extern "C" void kernel_launch(void* const* d_in, const int* in_sizes, int n_in,
                              void* d_out, int out_size, void* d_ws, size_t ws_size,
                              hipStream_t stream) {
    const float* x     = (const float*)d_in[0];
    const float* w_off = (const float*)d_in[1];
    const float* b_off = (const float*)d_in[2];
    const float* w_dc  = (const float*)d_in[3];
    const float* b_dc  = (const float*)d_in[4];
    const float* w_ca1 = (const float*)d_in[5];
    const float* b_ca1 = (const float*)d_in[6];
    const float* w_ca2 = (const float*)d_in[7];
    const float* b_ca2 = (const float*)d_in[8];
    const float* w_sa  = (const float*)d_in[9];
    const float* b_sa  = (const float*)d_in[10];
    const float* w_r1  = (const float*)d_in[11];
    const float* b_r1  = (const float*)d_in[12];
    const float* w_r2  = (const float*)d_in[13];
    const float* b_r2  = (const float*)d_in[14];
    const float* w_n1  = (const float*)d_in[15];
    const float* b_n1  = (const float*)d_in[16];
    const float* w_n2  = (const float*)d_in[17];
    const float* b_n2  = (const float*)d_in[18];
    const float* w_n3  = (const float*)d_in[19];
    const float* b_n3  = (const float*)d_in[20];
    float* out = (float*)d_out;

    float* ws = (float*)d_ws;
    float* xd    = ws;  ws += (size_t)B_ * CHW;          // 9437184
    float* om    = ws;  ws += (size_t)B_ * 27 * HW;      // 3981312
    float* sa    = ws;  ws += (size_t)B_ * HW;           // 147456
    float* ca_in = ws;  ws += 256;
    float* ca_o  = ws;  ws += 256;
    float* wdct  = ws;  ws += 64 * 64 * 9;               // 36864
    float* tr    = ws;  ws += (size_t)B_ * CHW;          // 9437184 (reused by n-branch)
    float* tn1 = tr;                                     // 4*32*HW = 4718592
    float* tn2 = tr + (size_t)B_ * 32 * HW;

    k_wdc_t<<<144, 256, 0, stream>>>(w_dc, wdct);
    k_conv_off<<<dim3(192, 27, 4), 192, 0, stream>>>(x, w_off, b_off, om);
    k_deform<<<dim3(HW / 32, 4), 256, 0, stream>>>(x, om, wdct, b_dc, xd);
    k_camean<<<256, 256, 0, stream>>>(xd, ca_in);
    k_ca_mlp<<<1, 256, 0, stream>>>(ca_in, w_ca1, b_ca1, w_ca2, b_ca2, ca_o);
    k_sa<<<dim3(192, 1, 4), 192, 0, stream>>>(xd, w_sa, b_sa, sa);
    k_scale<<<(B_ * CHW) / 256, 256, 0, stream>>>(xd, ca_o, sa);

    for (int j = 0; j < 4; ++j) {
        k_conv1x1<<<dim3(144, 64, 4), 256, 0, stream>>>(xd, w_r1, b_r1, tr, j * 64, 1);
        k_conv3x3_acc<<<dim3(192, 64, 4), 192, 0, stream>>>(tr, w_r2, b_r2, out, j);
    }

    k_conv1x1<<<dim3(144, 32, 4), 256, 0, stream>>>(xd, w_n1, b_n1, tn1, 0, 0);
    k_dw3x3<<<dim3(192, 32, 4), 192, 0, stream>>>(tn1, w_n2, b_n2, tn2);
    k_final<<<dim3(144, 64, 4), 256, 0, stream>>>(x, tn2, w_n3, b_n3, out);
}

// Round 4
// 1411.423 us; speedup vs baseline: 4.3421x; 4.3421x over previous
//
#include <hip/hip_runtime.h>
#include <hip/hip_bf16.h>
#include <math.h>

#define B_  4
#define C_  64
#define H_  192
#define W_  192
#define HW  36864           // H_*W_
#define CHW 2359296         // C_*HW

typedef __attribute__((ext_vector_type(8))) short short8;
typedef __attribute__((ext_vector_type(4))) float f32x4;

__device__ __forceinline__ float leakyf(float v) { return v >= 0.f ? v : 0.1f * v; }
__device__ __forceinline__ float sigmoidf_(float v) { return 1.f / (1.f + __expf(-v)); }
__device__ __forceinline__ unsigned short f2bf(float f) {
    union { float f; unsigned u; } v; v.f = f;
    unsigned r = v.u + 0x7fff + ((v.u >> 16) & 1);   // round-to-nearest-even
    return (unsigned short)(r >> 16);
}

// ---------------------------------------------------------------------------
// K0: transpose w_dc (o,c,k) -> (k,c,o) for coalesced LDS staging in deform
// ---------------------------------------------------------------------------
__global__ void k_wdc_t(const float* __restrict__ w, float* __restrict__ wt) {
    int i = blockIdx.x * 256 + threadIdx.x;   // 64*64*9 = 36864
    if (i < 64 * 64 * 9) {
        int k = i % 9;
        int c = (i / 9) % 64;
        int o = i / (9 * 64);
        wt[(k * 64 + c) * 64 + o] = w[i];
    }
}

// ---------------------------------------------------------------------------
// K0b: prepack r-branch weights to bf16.
// Apk1 = w_r1 [256][64] bf16. Apk2 = w_r2 repacked [64 oc][tap*256 + c] bf16.
// ---------------------------------------------------------------------------
__global__ void k_prepack(const float* __restrict__ w_r1, const float* __restrict__ w_r2,
                          unsigned short* __restrict__ Apk1, unsigned short* __restrict__ Apk2) {
    int t = blockIdx.x * 256 + threadIdx.x;
    if (t < 16384) Apk1[t] = f2bf(w_r1[t]);
    int e = t - 16384;
    if (e >= 0 && e < 147456) {
        int oc = e / 2304, r = e % 2304, tap = r / 256, c = r & 255;
        Apk2[e] = f2bf(w_r2[(oc * 256 + c) * 9 + tap]);
    }
}

// ---------------------------------------------------------------------------
// K1: offset/mask conv: 3x3, 64 -> 27, pad 1, leaky; ch>=18 additionally sigmoid
// ---------------------------------------------------------------------------
__global__ __launch_bounds__(192) void k_conv_off(const float* __restrict__ x,
                                                  const float* __restrict__ w,
                                                  const float* __restrict__ bias,
                                                  float* __restrict__ om) {
    int xc = threadIdx.x;
    int y  = blockIdx.x;
    int o  = blockIdx.y;
    int b  = blockIdx.z;
    const float* xb = x + (size_t)b * CHW;
    const float* wo = w + (size_t)o * C_ * 9;
    float acc = bias[o];
    for (int c = 0; c < C_; ++c) {
        const float* xcp = xb + c * HW;
        const float* wc  = wo + c * 9;
        #pragma unroll
        for (int dy = -1; dy <= 1; ++dy) {
            int yy = y + dy;
            if (yy < 0 || yy >= H_) continue;
            const float* row = xcp + yy * W_;
            #pragma unroll
            for (int dx = -1; dx <= 1; ++dx) {
                int xx = xc + dx;
                float v = (xx >= 0 && xx < W_) ? row[xx] : 0.f;
                acc += v * wc[(dy + 1) * 3 + (dx + 1)];
            }
        }
    }
    acc = leakyf(acc);
    if (o >= 18) acc = sigmoidf_(acc);
    om[((size_t)b * 27 + o) * HW + y * W_ + xc] = acc;
}

// ---------------------------------------------------------------------------
// K2: deformable conv (unchanged from R1)
// ---------------------------------------------------------------------------
__global__ __launch_bounds__(256) void k_deform(const float* __restrict__ x,
                                                const float* __restrict__ om,
                                                const float* __restrict__ wt,
                                                const float* __restrict__ bias,
                                                float* __restrict__ xd) {
    __shared__ float w_k[64 * 64];
    __shared__ float val[32 * 65];
    __shared__ int   sidx[4][32];
    __shared__ float swgt[4][32];

    int t  = threadIdx.x;
    int p  = t & 31;
    int og = t >> 5;
    int b  = blockIdx.y;
    int pix = blockIdx.x * 32 + p;
    int py_i = pix / W_;
    int px_i = pix - py_i * W_;

    float acc[8];
    #pragma unroll
    for (int i = 0; i < 8; ++i) acc[i] = bias[og * 8 + i];

    const float* xb  = x  + (size_t)b * CHW;
    const float* omb = om + (size_t)b * 27 * HW;

    for (int k = 0; k < 9; ++k) {
        __syncthreads();
        #pragma unroll
        for (int i = 0; i < 16; ++i) {
            int e = t + i * 256;
            w_k[e] = wt[k * 4096 + e];
        }
        if (t < 32) {
            float offy = omb[(size_t)(2 * k)     * HW + pix];
            float offx = omb[(size_t)(2 * k + 1) * HW + pix];
            float m    = omb[(size_t)(18 + k)    * HW + pix];
            float py = (float)py_i + (float)(k / 3 - 1) + offy;
            float px = (float)px_i + (float)(k % 3 - 1) + offx;
            float y0f = floorf(py), x0f = floorf(px);
            float wy = py - y0f, wx = px - x0f;
            int y0 = (int)y0f, x0 = (int)x0f;
            #pragma unroll
            for (int j = 0; j < 4; ++j) {
                int yy = y0 + (j >> 1);
                int xx = x0 + (j & 1);
                bool v = (yy >= 0) && (yy < H_) && (xx >= 0) && (xx < W_);
                int yc = min(max(yy, 0), H_ - 1);
                int xcl = min(max(xx, 0), W_ - 1);
                sidx[j][p] = yc * W_ + xcl;
                float wj = ((j >> 1) ? wy : 1.f - wy) * ((j & 1) ? wx : 1.f - wx);
                swgt[j][p] = v ? wj * m : 0.f;
            }
        }
        __syncthreads();
        #pragma unroll
        for (int i = 0; i < 8; ++i) {
            int e  = t + i * 256;
            int c  = e >> 5;
            int pp = e & 31;
            const float* xcp = xb + c * HW;
            float v = xcp[sidx[0][pp]] * swgt[0][pp]
                    + xcp[sidx[1][pp]] * swgt[1][pp]
                    + xcp[sidx[2][pp]] * swgt[2][pp]
                    + xcp[sidx[3][pp]] * swgt[3][pp];
            val[pp * 65 + c] = v;
        }
        __syncthreads();
        for (int c = 0; c < 64; ++c) {
            float v = val[p * 65 + c];
            #pragma unroll
            for (int i = 0; i < 8; ++i)
                acc[i] += v * w_k[c * 64 + og * 8 + i];
        }
    }
    #pragma unroll
    for (int i = 0; i < 8; ++i)
        xd[(size_t)b * CHW + (size_t)(og * 8 + i) * HW + pix] = acc[i];
}

// ---------------------------------------------------------------------------
// K3a/K3b: channel attention (unchanged)
// ---------------------------------------------------------------------------
__global__ __launch_bounds__(256) void k_camean(const float* __restrict__ xd,
                                                float* __restrict__ ca_in) {
    int bc = blockIdx.x;
    const float* ptr = xd + (size_t)bc * HW;
    float s = 0.f;
    for (int i = threadIdx.x; i < HW; i += 256) s += ptr[i];
    __shared__ float sm[256];
    sm[threadIdx.x] = s;
    __syncthreads();
    for (int st = 128; st > 0; st >>= 1) {
        if (threadIdx.x < st) sm[threadIdx.x] += sm[threadIdx.x + st];
        __syncthreads();
    }
    if (threadIdx.x == 0) ca_in[bc] = sm[0] * (1.f / (float)HW);
}

__global__ __launch_bounds__(256) void k_ca_mlp(const float* __restrict__ ca_in,
                                                const float* __restrict__ w1,
                                                const float* __restrict__ b1,
                                                const float* __restrict__ w2,
                                                const float* __restrict__ b2,
                                                float* __restrict__ ca_out) {
    __shared__ float h[32];
    int t = threadIdx.x;
    if (t < 32) {
        int b = t >> 3, j = t & 7;
        float a = b1[j];
        for (int c = 0; c < 64; ++c) a += w1[j * 64 + c] * ca_in[b * 64 + c];
        h[t] = a > 0.f ? a : 0.f;
    }
    __syncthreads();
    int b = t >> 6, c = t & 63;
    float a = b2[c];
    #pragma unroll
    for (int j = 0; j < 8; ++j) a += w2[c * 8 + j] * h[b * 8 + j];
    ca_out[t] = sigmoidf_(a);
}

// ---------------------------------------------------------------------------
// K4: spatial attention (unchanged)
// ---------------------------------------------------------------------------
__global__ __launch_bounds__(192) void k_sa(const float* __restrict__ xd,
                                            const float* __restrict__ w,
                                            const float* __restrict__ bias,
                                            float* __restrict__ sa) {
    int xc = threadIdx.x;
    int y  = blockIdx.x;
    int b  = blockIdx.z;
    const float* xb = xd + (size_t)b * CHW;
    float acc = bias[0];
    for (int c = 0; c < C_; ++c) {
        const float* xcp = xb + c * HW;
        const float* wc  = w + c * 9;
        #pragma unroll
        for (int dy = -1; dy <= 1; ++dy) {
            int yy = y + dy;
            if (yy < 0 || yy >= H_) continue;
            const float* row = xcp + yy * W_;
            #pragma unroll
            for (int dx = -1; dx <= 1; ++dx) {
                int xx = xc + dx;
                float v = (xx >= 0 && xx < W_) ? row[xx] : 0.f;
                acc += v * wc[(dy + 1) * 3 + (dx + 1)];
            }
        }
    }
    sa[(size_t)b * HW + y * W_ + xc] = sigmoidf_(acc);
}

// ---------------------------------------------------------------------------
// K5: xa = xd * (ca + sa): in-place on xd (fp32 NCHW for n-branch) AND
// transposed bf16 NHWC copy xa[(b,p)][64] for the MFMA r-branch.
// ---------------------------------------------------------------------------
__global__ __launch_bounds__(256) void k_scale_t(float* __restrict__ xd,
                                                 const float* __restrict__ ca,
                                                 const float* __restrict__ sa,
                                                 unsigned short* __restrict__ xa) {
    __shared__ unsigned short sT[64 * 72];
    int t  = threadIdx.x;
    int p0 = blockIdx.x * 64;
    int b  = blockIdx.y;
    const float* sab = sa + (size_t)b * HW + p0;
    float* xb = xd + (size_t)b * CHW + p0;
    #pragma unroll
    for (int i = 0; i < 16; ++i) {
        int e = t + i * 256;
        int c = e >> 6, pp = e & 63;
        float v = xb[(size_t)c * HW + pp];
        v *= (ca[b * 64 + c] + sab[pp]);
        xb[(size_t)c * HW + pp] = v;
        sT[pp * 72 + c] = f2bf(v);
    }
    __syncthreads();
    unsigned short* xap = xa + ((size_t)b * HW + p0) * 64;
    #pragma unroll
    for (int i = 0; i < 2; ++i) {
        int e = t + i * 256;
        int pp = e >> 3, cq = e & 7;
        *(uint4*)(xap + pp * 64 + cq * 8) = *(const uint4*)(sT + pp * 72 + cq * 8);
    }
}

// ---------------------------------------------------------------------------
// K6: r1 = leaky(1x1 conv 64->256) as bf16 MFMA GEMM, PER 1-BATCH SLAB.
// xa_s = slab base [HW pixels][64]; out tr [HW][256] bf16 NHWC.
// ---------------------------------------------------------------------------
__global__ __launch_bounds__(256) void k_r1_mfma(const unsigned short* __restrict__ xa_s,
                                                 const unsigned short* __restrict__ Apk1,
                                                 const float* __restrict__ b_r1,
                                                 unsigned short* __restrict__ tr) {
    int t    = threadIdx.x;
    int wv   = t >> 6;
    int lane = t & 63;
    int n    = lane & 15;
    int quad = lane >> 4;
    size_t p0 = (size_t)blockIdx.x * 64;

    f32x4 acc[4][4];
    #pragma unroll
    for (int i = 0; i < 4; ++i)
        #pragma unroll
        for (int j = 0; j < 4; ++j) acc[i][j] = (f32x4){0.f, 0.f, 0.f, 0.f};

    #pragma unroll
    for (int ks = 0; ks < 2; ++ks) {
        int k0 = ks * 32;
        short8 bfrag[4];
        #pragma unroll
        for (int jt = 0; jt < 4; ++jt)
            bfrag[jt] = *(const short8*)(xa_s + (p0 + jt * 16 + n) * 64 + k0 + quad * 8);
        #pragma unroll
        for (int mt = 0; mt < 4; ++mt) {
            short8 afrag = *(const short8*)(Apk1 + (wv * 64 + mt * 16 + n) * 64 + k0 + quad * 8);
            #pragma unroll
            for (int jt = 0; jt < 4; ++jt)
                acc[mt][jt] = __builtin_amdgcn_mfma_f32_16x16x32_bf16(afrag, bfrag[jt], acc[mt][jt], 0, 0, 0);
        }
    }
    #pragma unroll
    for (int mt = 0; mt < 4; ++mt) {
        int ocb = wv * 64 + mt * 16 + quad * 4;
        float b0 = b_r1[ocb], b1 = b_r1[ocb + 1], b2 = b_r1[ocb + 2], b3 = b_r1[ocb + 3];
        #pragma unroll
        for (int jt = 0; jt < 4; ++jt) {
            size_t p = p0 + jt * 16 + n;
            ushort4 pk;
            pk.x = f2bf(leakyf(acc[mt][jt][0] + b0));
            pk.y = f2bf(leakyf(acc[mt][jt][1] + b1));
            pk.z = f2bf(leakyf(acc[mt][jt][2] + b2));
            pk.w = f2bf(leakyf(acc[mt][jt][3] + b3));
            *(ushort4*)(tr + p * 256 + ocb) = pk;
        }
    }
}

// ---------------------------------------------------------------------------
// K7: r2 = 3x3 conv 256->64 bf16 MFMA, PER 1-BATCH SLAB, half-row blocks.
// Block: 64 oc x 96 x at one y. LDS: 3 rows x 98 cols x 32 c, pitch 40.
// grid = (2 x-halves, 192 rows).
// ---------------------------------------------------------------------------
#define R2P 40
__global__ __launch_bounds__(256) void k_r2_mfma(const unsigned short* __restrict__ tr,
                                                 const unsigned short* __restrict__ Apk2,
                                                 const float* __restrict__ b_r2,
                                                 float* __restrict__ out,
                                                 int b_glob) {
    __shared__ unsigned short sB[3 * 98 * R2P];   // 11760 shorts = 23520 B

    int t     = threadIdx.x;
    int wv    = t >> 6;
    int lane  = t & 63;
    int n     = lane & 15;
    int quad  = lane >> 4;
    int xh    = blockIdx.x;          // 0..1
    int y     = blockIdx.y;          // 0..191
    int x0    = xh * 96;
    int mbase = (wv & 1) * 32;
    int xbase = (wv >> 1) * 48;

    f32x4 acc[2][3];
    #pragma unroll
    for (int i = 0; i < 2; ++i)
        #pragma unroll
        for (int j = 0; j < 3; ++j) acc[i][j] = (f32x4){0.f, 0.f, 0.f, 0.f};

    for (int c0 = 0; c0 < 256; c0 += 32) {
        __syncthreads();
        // stage 3 rows x 98 cols x 32 c: 1176 x 16B loads
        #pragma unroll
        for (int i = 0; i < 5; ++i) {
            int e = t + i * 256;
            if (e < 1176) {
                int r   = e / 392;
                int rem = e - r * 392;
                int xi  = rem >> 2;
                int cq  = rem & 3;
                int yy  = y + r - 1;
                int xx  = x0 - 1 + xi;
                uint4 v = make_uint4(0u, 0u, 0u, 0u);
                if (yy >= 0 && yy < H_ && xx >= 0 && xx < W_)
                    v = *(const uint4*)(tr + ((size_t)yy * W_ + xx) * 256 + c0 + cq * 8);
                *(uint4*)(sB + (r * 98 + xi) * R2P + cq * 8) = v;
            }
        }
        __syncthreads();
        #pragma unroll
        for (int tap = 0; tap < 9; ++tap) {
            int dy = tap / 3, dx = tap % 3;
            short8 a0 = *(const short8*)(Apk2 + (size_t)(mbase + n)      * 2304 + tap * 256 + c0 + quad * 8);
            short8 a1 = *(const short8*)(Apk2 + (size_t)(mbase + 16 + n) * 2304 + tap * 256 + c0 + quad * 8);
            #pragma unroll
            for (int j = 0; j < 3; ++j) {
                int xi = xbase + j * 16 + n + dx;   // sB col; input x = x0-1+xi
                short8 bf = *(const short8*)(sB + (dy * 98 + xi) * R2P + quad * 8);
                acc[0][j] = __builtin_amdgcn_mfma_f32_16x16x32_bf16(a0, bf, acc[0][j], 0, 0, 0);
                acc[1][j] = __builtin_amdgcn_mfma_f32_16x16x32_bf16(a1, bf, acc[1][j], 0, 0, 0);
            }
        }
    }
    #pragma unroll
    for (int mt = 0; mt < 2; ++mt) {
        int oc = mbase + mt * 16 + quad * 4;
        float b0 = b_r2[oc], b1 = b_r2[oc + 1], b2 = b_r2[oc + 2], b3 = b_r2[oc + 3];
        #pragma unroll
        for (int j = 0; j < 3; ++j) {
            int xx = x0 + xbase + j * 16 + n;
            float* op = out + ((size_t)b_glob * 64 + oc) * HW + y * W_ + xx;
            op[0]              = acc[mt][j][0] + b0;
            op[HW]             = acc[mt][j][1] + b1;
            op[2 * HW]         = acc[mt][j][2] + b2;
            op[3 * (size_t)HW] = acc[mt][j][3] + b3;
        }
    }
}

// ---------------------------------------------------------------------------
// K8: 1x1 conv (n-branch n1 only)
// ---------------------------------------------------------------------------
__global__ __launch_bounds__(256) void k_conv1x1(const float* __restrict__ in,
                                                 const float* __restrict__ w,
                                                 const float* __restrict__ bias,
                                                 float* __restrict__ out,
                                                 int oc_base, int do_leaky) {
    int p  = blockIdx.x * 256 + threadIdx.x;
    int oc = blockIdx.y;
    int nc = gridDim.y;
    int b  = blockIdx.z;
    int go = oc_base + oc;
    const float* xb = in + (size_t)b * CHW + p;
    const float* wo = w + (size_t)go * 64;
    float acc = bias[go];
    #pragma unroll 8
    for (int c = 0; c < 64; ++c) acc += xb[(size_t)c * HW] * wo[c];
    if (do_leaky) acc = leakyf(acc);
    out[((size_t)b * nc + oc) * HW + p] = acc;
}

// ---------------------------------------------------------------------------
// K9: depthwise 3x3 (unchanged)
// ---------------------------------------------------------------------------
__global__ __launch_bounds__(192) void k_dw3x3(const float* __restrict__ t1,
                                               const float* __restrict__ w,
                                               const float* __restrict__ bias,
                                               float* __restrict__ t2) {
    int xc = threadIdx.x;
    int y  = blockIdx.x;
    int c  = blockIdx.y;
    int b  = blockIdx.z;
    const float* src = t1 + ((size_t)b * 32 + c) * HW;
    const float* wc  = w + c * 9;
    float acc = bias[c];
    #pragma unroll
    for (int dy = -1; dy <= 1; ++dy) {
        int yy = y + dy;
        if (yy < 0 || yy >= H_) continue;
        const float* row = src + yy * W_;
        #pragma unroll
        for (int dx = -1; dx <= 1; ++dx) {
            int xx = xc + dx;
            float v = (xx >= 0 && xx < W_) ? row[xx] : 0.f;
            acc += v * wc[(dy + 1) * 3 + (dx + 1)];
        }
    }
    t2[((size_t)b * 32 + c) * HW + y * W_ + xc] = acc;
}

// ---------------------------------------------------------------------------
// K10: out = x + xr(in d_out) + (w_n3 @ t2 + b_n3)
// ---------------------------------------------------------------------------
__global__ __launch_bounds__(256) void k_final(const float* __restrict__ x,
                                               const float* __restrict__ t2,
                                               const float* __restrict__ w,
                                               const float* __restrict__ bias,
                                               float* __restrict__ out) {
    int p  = blockIdx.x * 256 + threadIdx.x;
    int oc = blockIdx.y;
    int b  = blockIdx.z;
    const float* tb = t2 + (size_t)b * 32 * HW + p;
    const float* wo = w + oc * 32;
    float acc = bias[oc];
    #pragma unroll 8
    for (int c = 0; c < 32; ++c) acc += tb[(size_t)c * HW] * wo[c];
    size_t idx = ((size_t)b * 64 + oc) * HW + p;
    out[idx] = x[idx] + out[idx] + acc;
}

// ---------------------------------------------------------------------------
extern "C" void kernel_launch(void* const* d_in, const int* in_sizes, int n_in,
                              void* d_out, int out_size, void* d_ws, size_t ws_size,
                              hipStream_t stream) {
    const float* x     = (const float*)d_in[0];
    const float* w_off = (const float*)d_in[1];
    const float* b_off = (const float*)d_in[2];
    const float* w_dc  = (const float*)d_in[3];
    const float* b_dc  = (const float*)d_in[4];
    const float* w_ca1 = (const float*)d_in[5];
    const float* b_ca1 = (const float*)d_in[6];
    const float* w_ca2 = (const float*)d_in[7];
    const float* b_ca2 = (const float*)d_in[8];
    const float* w_sa  = (const float*)d_in[9];
    const float* b_sa  = (const float*)d_in[10];
    const float* w_r1  = (const float*)d_in[11];
    const float* b_r1  = (const float*)d_in[12];
    const float* w_r2  = (const float*)d_in[13];
    const float* b_r2  = (const float*)d_in[14];
    const float* w_n1  = (const float*)d_in[15];
    const float* b_n1  = (const float*)d_in[16];
    const float* w_n2  = (const float*)d_in[17];
    const float* b_n2  = (const float*)d_in[18];
    const float* w_n3  = (const float*)d_in[19];
    const float* b_n3  = (const float*)d_in[20];
    float* out = (float*)d_out;

    // ------------------------------------------------------------------
    // Workspace layout (float offsets). Total 19,141,120 f = 76.6 MB
    // (< 92.2 MB proven in R1). Disjointness audited:
    //   A [0,        9437184)  xd fp32 (xa fp32 after scale); tn2 overlays
    //                          [0, 4718592) only after n1 consumed xd.
    //   B [9437184, 14155776)  om fp32 (3981312 f, dead after deform) then
    //                          xa bf16 (9437184 shorts = 4718592 f, exact).
    //   C [14155776,14303232)  sa fp32
    //   D [14303232,14422528)  ca_in, ca_o, wdct, Apk1 (bf16), Apk2 (bf16)
    //   E [14422528,19141120)  tr 1-batch bf16 (9437184 shorts); tn1 after.
    // ------------------------------------------------------------------
    float* ws = (float*)d_ws;
    float* xd    = ws;
    float* om    = ws + 9437184;
    float* sa    = ws + 14155776;
    float* ca_in = ws + 14303232;
    float* ca_o  = ws + 14303488;
    float* wdct  = ws + 14303744;
    unsigned short* Apk1 = (unsigned short*)(ws + 14340608);  // 16384 shorts
    unsigned short* Apk2 = (unsigned short*)(ws + 14348800);  // 147456 shorts
    float* trE   = ws + 14422528;

    unsigned short* xa_bhwc = (unsigned short*)om;            // 9437184 shorts
    unsigned short* trh     = (unsigned short*)trE;           // 9437184 shorts
    float* tn1 = trE;                                         // 4718592 f (after r-branch)
    float* tn2 = ws;                                          // 4718592 f (after n1)

    k_wdc_t   <<<144, 256, 0, stream>>>(w_dc, wdct);
    k_conv_off<<<dim3(192, 27, 4), 192, 0, stream>>>(x, w_off, b_off, om);
    k_deform  <<<dim3(HW / 32, 4), 256, 0, stream>>>(x, om, wdct, b_dc, xd);
    k_prepack <<<640, 256, 0, stream>>>(w_r1, w_r2, Apk1, Apk2);
    k_camean  <<<256, 256, 0, stream>>>(xd, ca_in);
    k_ca_mlp  <<<1, 256, 0, stream>>>(ca_in, w_ca1, b_ca1, w_ca2, b_ca2, ca_o);
    k_sa      <<<dim3(192, 1, 4), 192, 0, stream>>>(xd, w_sa, b_sa, sa);
    k_scale_t <<<dim3(HW / 64, 4), 256, 0, stream>>>(xd, ca_o, sa, xa_bhwc);

    // r-branch: four 1-batch slabs through the same tr buffer (stream-serialized)
    for (int b = 0; b < 4; ++b) {
        k_r1_mfma<<<HW / 64, 256, 0, stream>>>(xa_bhwc + (size_t)b * HW * 64,
                                               Apk1, b_r1, trh);
        k_r2_mfma<<<dim3(2, 192), 256, 0, stream>>>(trh, Apk2, b_r2, out, b);
    }

    // n-branch: tn1 overlays tr (dead), tn2 overlays xd (dead after n1)
    k_conv1x1 <<<dim3(144, 32, 4), 256, 0, stream>>>(xd, w_n1, b_n1, tn1, 0, 0);
    k_dw3x3   <<<dim3(192, 32, 4), 192, 0, stream>>>(tn1, w_n2, b_n2, tn2);
    k_final   <<<dim3(144, 64, 4), 256, 0, stream>>>(x, tn2, w_n3, b_n3, out);
}

// Round 5
// 886.672 us; speedup vs baseline: 6.9118x; 1.5918x over previous
//
#include <hip/hip_runtime.h>
#include <hip/hip_bf16.h>
#include <math.h>

#define B_  4
#define C_  64
#define H_  192
#define W_  192
#define HW  36864           // H_*W_
#define CHW 2359296         // C_*HW

typedef __attribute__((ext_vector_type(8))) short short8;
typedef __attribute__((ext_vector_type(4))) float f32x4;

__device__ __forceinline__ float leakyf(float v) { return v >= 0.f ? v : 0.1f * v; }
__device__ __forceinline__ float sigmoidf_(float v) { return 1.f / (1.f + __expf(-v)); }
__device__ __forceinline__ unsigned short f2bf(float f) {
    union { float f; unsigned u; } v; v.f = f;
    unsigned r = v.u + 0x7fff + ((v.u >> 16) & 1);   // round-to-nearest-even
    return (unsigned short)(r >> 16);
}
__device__ __forceinline__ float bf2f(unsigned short s) {
    union { unsigned u; float f; } cv; cv.u = ((unsigned)s) << 16; return cv.f;
}

// ---------------------------------------------------------------------------
// K-1: x (NCHW fp32) -> x_bhwc (NHWC bf16) via LDS transpose
// ---------------------------------------------------------------------------
__global__ __launch_bounds__(256) void k_x_t(const float* __restrict__ x,
                                             unsigned short* __restrict__ xb16) {
    __shared__ unsigned short sT[64 * 72];
    int t  = threadIdx.x;
    int p0 = blockIdx.x * 64;
    int b  = blockIdx.y;
    const float* xb = x + (size_t)b * CHW + p0;
    #pragma unroll
    for (int i = 0; i < 16; ++i) {
        int e = t + i * 256;
        int c = e >> 6, pp = e & 63;
        sT[pp * 72 + c] = f2bf(xb[(size_t)c * HW + pp]);
    }
    __syncthreads();
    unsigned short* xap = xb16 + ((size_t)b * HW + p0) * 64;
    #pragma unroll
    for (int i = 0; i < 2; ++i) {
        int e = t + i * 256;
        int pp = e >> 3, cq = e & 7;
        *(uint4*)(xap + pp * 64 + cq * 8) = *(const uint4*)(sT + pp * 72 + cq * 8);
    }
}

// ---------------------------------------------------------------------------
// K0: transpose w_dc (o,c,k) -> (k,c,o) for coalesced LDS staging in deform
// ---------------------------------------------------------------------------
__global__ void k_wdc_t(const float* __restrict__ w, float* __restrict__ wt) {
    int i = blockIdx.x * 256 + threadIdx.x;   // 64*64*9 = 36864
    if (i < 64 * 64 * 9) {
        int k = i % 9;
        int c = (i / 9) % 64;
        int o = i / (9 * 64);
        wt[(k * 64 + c) * 64 + o] = w[i];
    }
}

// ---------------------------------------------------------------------------
// K0b: prepack weights to bf16.
// Apk1 = w_r1 [256][64]. Apk2 = w_r2 [64 oc][tap*256+c].
// Wofpk = w_off [32 (27 pad)][tap*64+c].
// ---------------------------------------------------------------------------
__global__ void k_prepack(const float* __restrict__ w_r1, const float* __restrict__ w_r2,
                          const float* __restrict__ w_off,
                          unsigned short* __restrict__ Apk1, unsigned short* __restrict__ Apk2,
                          unsigned short* __restrict__ Wofpk) {
    int t = blockIdx.x * 256 + threadIdx.x;
    if (t < 16384) Apk1[t] = f2bf(w_r1[t]);
    int e = t - 16384;
    if (e >= 0 && e < 147456) {
        int oc = e / 2304, r = e % 2304, tap = r / 256, c = r & 255;
        Apk2[e] = f2bf(w_r2[(oc * 256 + c) * 9 + tap]);
    }
    int e2 = t - 163840;
    if (e2 >= 0 && e2 < 18432) {
        int m = e2 / 576, r = e2 % 576, tap = r / 64, c = r & 63;
        Wofpk[e2] = (m < 27) ? f2bf(w_off[m * 576 + c * 9 + tap]) : (unsigned short)0;
    }
}

// ---------------------------------------------------------------------------
// K1: offset/mask conv as bf16 implicit-GEMM MFMA. M=32 (27 real oc),
// N=64 x-cols per block, K=9 taps x 64 c. Block=(64 x at one (b,y)).
// LDS: 3 rows x 66 cols x 64 c, pitch 72 (16B-aligned, 2-way banks).
// grid = (3, 192, 4).
// ---------------------------------------------------------------------------
__global__ __launch_bounds__(256) void k_off_mfma(const unsigned short* __restrict__ xb16,
                                                  const unsigned short* __restrict__ Wofpk,
                                                  const float* __restrict__ b_off,
                                                  float* __restrict__ om) {
    __shared__ unsigned short sB[3 * 66 * 72];   // 28512 B

    int t    = threadIdx.x;
    int wv   = t >> 6;
    int lane = t & 63;
    int n    = lane & 15;
    int quad = lane >> 4;
    int x0   = blockIdx.x * 64;
    int y    = blockIdx.y;
    int b    = blockIdx.z;
    int xn   = wv * 16;

    // stage 3 rows x 66 cols x 64 c (1584 x 16B)
    #pragma unroll
    for (int i = 0; i < 7; ++i) {
        int e = t + i * 256;
        if (e < 1584) {
            int r   = e / 528;
            int rem = e - r * 528;
            int xi  = rem >> 3;
            int cg  = rem & 7;
            int yy  = y + r - 1;
            int xx  = x0 - 1 + xi;
            uint4 v = make_uint4(0u, 0u, 0u, 0u);
            if (yy >= 0 && yy < H_ && xx >= 0 && xx < W_)
                v = *(const uint4*)(xb16 + ((size_t)b * HW + (size_t)yy * W_ + xx) * 64 + cg * 8);
            *(uint4*)(sB + (r * 66 + xi) * 72 + cg * 8) = v;
        }
    }
    __syncthreads();

    f32x4 acc[2];
    acc[0] = (f32x4){0.f, 0.f, 0.f, 0.f};
    acc[1] = (f32x4){0.f, 0.f, 0.f, 0.f};

    #pragma unroll
    for (int tap = 0; tap < 9; ++tap) {
        int dy = tap / 3, dx = tap % 3;
        #pragma unroll
        for (int kc = 0; kc < 2; ++kc) {
            short8 a0 = *(const short8*)(Wofpk + (size_t)n        * 576 + tap * 64 + kc * 32 + quad * 8);
            short8 a1 = *(const short8*)(Wofpk + (size_t)(16 + n) * 576 + tap * 64 + kc * 32 + quad * 8);
            short8 bf = *(const short8*)(sB + (dy * 66 + xn + n + dx) * 72 + kc * 32 + quad * 8);
            acc[0] = __builtin_amdgcn_mfma_f32_16x16x32_bf16(a0, bf, acc[0], 0, 0, 0);
            acc[1] = __builtin_amdgcn_mfma_f32_16x16x32_bf16(a1, bf, acc[1], 0, 0, 0);
        }
    }

    int xx = x0 + xn + n;
    #pragma unroll
    for (int mt = 0; mt < 2; ++mt) {
        #pragma unroll
        for (int reg = 0; reg < 4; ++reg) {
            int oc = mt * 16 + quad * 4 + reg;
            if (oc < 27) {
                float v = leakyf(acc[mt][reg] + b_off[oc]);
                if (oc >= 18) v = sigmoidf_(v);
                om[((size_t)b * 27 + oc) * HW + (size_t)y * W_ + xx] = v;
            }
        }
    }
}

// ---------------------------------------------------------------------------
// K2: deformable conv — gathers now from x_bhwc (NHWC bf16), MAC fp32.
// ---------------------------------------------------------------------------
__global__ __launch_bounds__(256) void k_deform(const unsigned short* __restrict__ xb16,
                                                const float* __restrict__ om,
                                                const float* __restrict__ wt,
                                                const float* __restrict__ bias,
                                                float* __restrict__ xd) {
    __shared__ float w_k[64 * 64];
    __shared__ float val[32 * 65];
    __shared__ int   sidx[4][32];
    __shared__ float swgt[4][32];

    int t  = threadIdx.x;
    int p  = t & 31;
    int og = t >> 5;
    int b  = blockIdx.y;
    int pix = blockIdx.x * 32 + p;
    int py_i = pix / W_;
    int px_i = pix - py_i * W_;

    float acc[8];
    #pragma unroll
    for (int i = 0; i < 8; ++i) acc[i] = bias[og * 8 + i];

    const unsigned short* xbh = xb16 + (size_t)b * HW * 64 + (t >> 5) * 8;
    const float* omb = om + (size_t)b * 27 * HW;

    for (int k = 0; k < 9; ++k) {
        __syncthreads();
        #pragma unroll
        for (int i = 0; i < 16; ++i) {
            int e = t + i * 256;
            w_k[e] = wt[k * 4096 + e];
        }
        if (t < 32) {
            float offy = omb[(size_t)(2 * k)     * HW + pix];
            float offx = omb[(size_t)(2 * k + 1) * HW + pix];
            float m    = omb[(size_t)(18 + k)    * HW + pix];
            float py = (float)py_i + (float)(k / 3 - 1) + offy;
            float px = (float)px_i + (float)(k % 3 - 1) + offx;
            float y0f = floorf(py), x0f = floorf(px);
            float wy = py - y0f, wx = px - x0f;
            int y0 = (int)y0f, x0 = (int)x0f;
            #pragma unroll
            for (int j = 0; j < 4; ++j) {
                int yy = y0 + (j >> 1);
                int xx = x0 + (j & 1);
                bool v = (yy >= 0) && (yy < H_) && (xx >= 0) && (xx < W_);
                int yc = min(max(yy, 0), H_ - 1);
                int xcl = min(max(xx, 0), W_ - 1);
                sidx[j][p] = yc * W_ + xcl;
                float wj = ((j >> 1) ? wy : 1.f - wy) * ((j & 1) ? wx : 1.f - wx);
                swgt[j][p] = v ? wj * m : 0.f;
            }
        }
        __syncthreads();
        // bilinear sample: thread = (pp = t&31, cg = t>>5), 4 x b128 gathers
        {
            int pp = t & 31;
            float vf[8] = {0.f, 0.f, 0.f, 0.f, 0.f, 0.f, 0.f, 0.f};
            #pragma unroll
            for (int j = 0; j < 4; ++j) {
                float w = swgt[j][pp];
                short8 s = *(const short8*)(xbh + (size_t)sidx[j][pp] * 64);
                #pragma unroll
                for (int q = 0; q < 8; ++q)
                    vf[q] += w * bf2f((unsigned short)s[q]);
            }
            #pragma unroll
            for (int q = 0; q < 8; ++q)
                val[pp * 65 + (t >> 5) * 8 + q] = vf[q];
        }
        __syncthreads();
        for (int c = 0; c < 64; ++c) {
            float v = val[p * 65 + c];
            #pragma unroll
            for (int i = 0; i < 8; ++i)
                acc[i] += v * w_k[c * 64 + og * 8 + i];
        }
    }
    #pragma unroll
    for (int i = 0; i < 8; ++i)
        xd[(size_t)b * CHW + (size_t)(og * 8 + i) * HW + pix] = acc[i];
}

// ---------------------------------------------------------------------------
// K3a/K3b: channel attention (unchanged)
// ---------------------------------------------------------------------------
__global__ __launch_bounds__(256) void k_camean(const float* __restrict__ xd,
                                                float* __restrict__ ca_in) {
    int bc = blockIdx.x;
    const float* ptr = xd + (size_t)bc * HW;
    float s = 0.f;
    for (int i = threadIdx.x; i < HW; i += 256) s += ptr[i];
    __shared__ float sm[256];
    sm[threadIdx.x] = s;
    __syncthreads();
    for (int st = 128; st > 0; st >>= 1) {
        if (threadIdx.x < st) sm[threadIdx.x] += sm[threadIdx.x + st];
        __syncthreads();
    }
    if (threadIdx.x == 0) ca_in[bc] = sm[0] * (1.f / (float)HW);
}

__global__ __launch_bounds__(256) void k_ca_mlp(const float* __restrict__ ca_in,
                                                const float* __restrict__ w1,
                                                const float* __restrict__ b1,
                                                const float* __restrict__ w2,
                                                const float* __restrict__ b2,
                                                float* __restrict__ ca_out) {
    __shared__ float h[32];
    int t = threadIdx.x;
    if (t < 32) {
        int b = t >> 3, j = t & 7;
        float a = b1[j];
        for (int c = 0; c < 64; ++c) a += w1[j * 64 + c] * ca_in[b * 64 + c];
        h[t] = a > 0.f ? a : 0.f;
    }
    __syncthreads();
    int b = t >> 6, c = t & 63;
    float a = b2[c];
    #pragma unroll
    for (int j = 0; j < 8; ++j) a += w2[c * 8 + j] * h[b * 8 + j];
    ca_out[t] = sigmoidf_(a);
}

// ---------------------------------------------------------------------------
// K4: spatial attention (unchanged)
// ---------------------------------------------------------------------------
__global__ __launch_bounds__(192) void k_sa(const float* __restrict__ xd,
                                            const float* __restrict__ w,
                                            const float* __restrict__ bias,
                                            float* __restrict__ sa) {
    int xc = threadIdx.x;
    int y  = blockIdx.x;
    int b  = blockIdx.z;
    const float* xb = xd + (size_t)b * CHW;
    float acc = bias[0];
    for (int c = 0; c < C_; ++c) {
        const float* xcp = xb + c * HW;
        const float* wc  = w + c * 9;
        #pragma unroll
        for (int dy = -1; dy <= 1; ++dy) {
            int yy = y + dy;
            if (yy < 0 || yy >= H_) continue;
            const float* row = xcp + yy * W_;
            #pragma unroll
            for (int dx = -1; dx <= 1; ++dx) {
                int xx = xc + dx;
                float v = (xx >= 0 && xx < W_) ? row[xx] : 0.f;
                acc += v * wc[(dy + 1) * 3 + (dx + 1)];
            }
        }
    }
    sa[(size_t)b * HW + y * W_ + xc] = sigmoidf_(acc);
}

// ---------------------------------------------------------------------------
// K5: xa = xd * (ca + sa): in-place on xd (fp32 NCHW for n-branch) AND
// transposed bf16 NHWC copy xa[(b,p)][64] for the MFMA r-branch.
// ---------------------------------------------------------------------------
__global__ __launch_bounds__(256) void k_scale_t(float* __restrict__ xd,
                                                 const float* __restrict__ ca,
                                                 const float* __restrict__ sa,
                                                 unsigned short* __restrict__ xa) {
    __shared__ unsigned short sT[64 * 72];
    int t  = threadIdx.x;
    int p0 = blockIdx.x * 64;
    int b  = blockIdx.y;
    const float* sab = sa + (size_t)b * HW + p0;
    float* xb = xd + (size_t)b * CHW + p0;
    #pragma unroll
    for (int i = 0; i < 16; ++i) {
        int e = t + i * 256;
        int c = e >> 6, pp = e & 63;
        float v = xb[(size_t)c * HW + pp];
        v *= (ca[b * 64 + c] + sab[pp]);
        xb[(size_t)c * HW + pp] = v;
        sT[pp * 72 + c] = f2bf(v);
    }
    __syncthreads();
    unsigned short* xap = xa + ((size_t)b * HW + p0) * 64;
    #pragma unroll
    for (int i = 0; i < 2; ++i) {
        int e = t + i * 256;
        int pp = e >> 3, cq = e & 7;
        *(uint4*)(xap + pp * 64 + cq * 8) = *(const uint4*)(sT + pp * 72 + cq * 8);
    }
}

// ---------------------------------------------------------------------------
// K6: r1 = leaky(1x1 conv 64->256) as bf16 MFMA GEMM, PER 1-BATCH SLAB.
// ---------------------------------------------------------------------------
__global__ __launch_bounds__(256) void k_r1_mfma(const unsigned short* __restrict__ xa_s,
                                                 const unsigned short* __restrict__ Apk1,
                                                 const float* __restrict__ b_r1,
                                                 unsigned short* __restrict__ tr) {
    int t    = threadIdx.x;
    int wv   = t >> 6;
    int lane = t & 63;
    int n    = lane & 15;
    int quad = lane >> 4;
    size_t p0 = (size_t)blockIdx.x * 64;

    f32x4 acc[4][4];
    #pragma unroll
    for (int i = 0; i < 4; ++i)
        #pragma unroll
        for (int j = 0; j < 4; ++j) acc[i][j] = (f32x4){0.f, 0.f, 0.f, 0.f};

    #pragma unroll
    for (int ks = 0; ks < 2; ++ks) {
        int k0 = ks * 32;
        short8 bfrag[4];
        #pragma unroll
        for (int jt = 0; jt < 4; ++jt)
            bfrag[jt] = *(const short8*)(xa_s + (p0 + jt * 16 + n) * 64 + k0 + quad * 8);
        #pragma unroll
        for (int mt = 0; mt < 4; ++mt) {
            short8 afrag = *(const short8*)(Apk1 + (wv * 64 + mt * 16 + n) * 64 + k0 + quad * 8);
            #pragma unroll
            for (int jt = 0; jt < 4; ++jt)
                acc[mt][jt] = __builtin_amdgcn_mfma_f32_16x16x32_bf16(afrag, bfrag[jt], acc[mt][jt], 0, 0, 0);
        }
    }
    #pragma unroll
    for (int mt = 0; mt < 4; ++mt) {
        int ocb = wv * 64 + mt * 16 + quad * 4;
        float b0 = b_r1[ocb], b1 = b_r1[ocb + 1], b2 = b_r1[ocb + 2], b3 = b_r1[ocb + 3];
        #pragma unroll
        for (int jt = 0; jt < 4; ++jt) {
            size_t p = p0 + jt * 16 + n;
            ushort4 pk;
            pk.x = f2bf(leakyf(acc[mt][jt][0] + b0));
            pk.y = f2bf(leakyf(acc[mt][jt][1] + b1));
            pk.z = f2bf(leakyf(acc[mt][jt][2] + b2));
            pk.w = f2bf(leakyf(acc[mt][jt][3] + b3));
            *(ushort4*)(tr + p * 256 + ocb) = pk;
        }
    }
}

// ---------------------------------------------------------------------------
// K7: r2 = 3x3 conv 256->64 bf16 MFMA, PER 1-BATCH SLAB, half-row blocks.
// ---------------------------------------------------------------------------
#define R2P 40
__global__ __launch_bounds__(256) void k_r2_mfma(const unsigned short* __restrict__ tr,
                                                 const unsigned short* __restrict__ Apk2,
                                                 const float* __restrict__ b_r2,
                                                 float* __restrict__ out,
                                                 int b_glob) {
    __shared__ unsigned short sB[3 * 98 * R2P];   // 23520 B

    int t     = threadIdx.x;
    int wv    = t >> 6;
    int lane  = t & 63;
    int n     = lane & 15;
    int quad  = lane >> 4;
    int xh    = blockIdx.x;
    int y     = blockIdx.y;
    int x0    = xh * 96;
    int mbase = (wv & 1) * 32;
    int xbase = (wv >> 1) * 48;

    f32x4 acc[2][3];
    #pragma unroll
    for (int i = 0; i < 2; ++i)
        #pragma unroll
        for (int j = 0; j < 3; ++j) acc[i][j] = (f32x4){0.f, 0.f, 0.f, 0.f};

    for (int c0 = 0; c0 < 256; c0 += 32) {
        __syncthreads();
        #pragma unroll
        for (int i = 0; i < 5; ++i) {
            int e = t + i * 256;
            if (e < 1176) {
                int r   = e / 392;
                int rem = e - r * 392;
                int xi  = rem >> 2;
                int cq  = rem & 3;
                int yy  = y + r - 1;
                int xx  = x0 - 1 + xi;
                uint4 v = make_uint4(0u, 0u, 0u, 0u);
                if (yy >= 0 && yy < H_ && xx >= 0 && xx < W_)
                    v = *(const uint4*)(tr + ((size_t)yy * W_ + xx) * 256 + c0 + cq * 8);
                *(uint4*)(sB + (r * 98 + xi) * R2P + cq * 8) = v;
            }
        }
        __syncthreads();
        #pragma unroll
        for (int tap = 0; tap < 9; ++tap) {
            int dy = tap / 3, dx = tap % 3;
            short8 a0 = *(const short8*)(Apk2 + (size_t)(mbase + n)      * 2304 + tap * 256 + c0 + quad * 8);
            short8 a1 = *(const short8*)(Apk2 + (size_t)(mbase + 16 + n) * 2304 + tap * 256 + c0 + quad * 8);
            #pragma unroll
            for (int j = 0; j < 3; ++j) {
                int xi = xbase + j * 16 + n + dx;
                short8 bf = *(const short8*)(sB + (dy * 98 + xi) * R2P + quad * 8);
                acc[0][j] = __builtin_amdgcn_mfma_f32_16x16x32_bf16(a0, bf, acc[0][j], 0, 0, 0);
                acc[1][j] = __builtin_amdgcn_mfma_f32_16x16x32_bf16(a1, bf, acc[1][j], 0, 0, 0);
            }
        }
    }
    #pragma unroll
    for (int mt = 0; mt < 2; ++mt) {
        int oc = mbase + mt * 16 + quad * 4;
        float b0 = b_r2[oc], b1 = b_r2[oc + 1], b2 = b_r2[oc + 2], b3 = b_r2[oc + 3];
        #pragma unroll
        for (int j = 0; j < 3; ++j) {
            int xx = x0 + xbase + j * 16 + n;
            float* op = out + ((size_t)b_glob * 64 + oc) * HW + y * W_ + xx;
            op[0]              = acc[mt][j][0] + b0;
            op[HW]             = acc[mt][j][1] + b1;
            op[2 * HW]         = acc[mt][j][2] + b2;
            op[3 * (size_t)HW] = acc[mt][j][3] + b3;
        }
    }
}

// ---------------------------------------------------------------------------
// K8: 1x1 conv (n-branch n1 only)
// ---------------------------------------------------------------------------
__global__ __launch_bounds__(256) void k_conv1x1(const float* __restrict__ in,
                                                 const float* __restrict__ w,
                                                 const float* __restrict__ bias,
                                                 float* __restrict__ out,
                                                 int oc_base, int do_leaky) {
    int p  = blockIdx.x * 256 + threadIdx.x;
    int oc = blockIdx.y;
    int nc = gridDim.y;
    int b  = blockIdx.z;
    int go = oc_base + oc;
    const float* xb = in + (size_t)b * CHW + p;
    const float* wo = w + (size_t)go * 64;
    float acc = bias[go];
    #pragma unroll 8
    for (int c = 0; c < 64; ++c) acc += xb[(size_t)c * HW] * wo[c];
    if (do_leaky) acc = leakyf(acc);
    out[((size_t)b * nc + oc) * HW + p] = acc;
}

// ---------------------------------------------------------------------------
// K9: depthwise 3x3 (unchanged)
// ---------------------------------------------------------------------------
__global__ __launch_bounds__(192) void k_dw3x3(const float* __restrict__ t1,
                                               const float* __restrict__ w,
                                               const float* __restrict__ bias,
                                               float* __restrict__ t2) {
    int xc = threadIdx.x;
    int y  = blockIdx.x;
    int c  = blockIdx.y;
    int b  = blockIdx.z;
    const float* src = t1 + ((size_t)b * 32 + c) * HW;
    const float* wc  = w + c * 9;
    float acc = bias[c];
    #pragma unroll
    for (int dy = -1; dy <= 1; ++dy) {
        int yy = y + dy;
        if (yy < 0 || yy >= H_) continue;
        const float* row = src + yy * W_;
        #pragma unroll
        for (int dx = -1; dx <= 1; ++dx) {
            int xx = xc + dx;
            float v = (xx >= 0 && xx < W_) ? row[xx] : 0.f;
            acc += v * wc[(dy + 1) * 3 + (dx + 1)];
        }
    }
    t2[((size_t)b * 32 + c) * HW + y * W_ + xc] = acc;
}

// ---------------------------------------------------------------------------
// K10: out = x + xr(in d_out) + (w_n3 @ t2 + b_n3)
// ---------------------------------------------------------------------------
__global__ __launch_bounds__(256) void k_final(const float* __restrict__ x,
                                               const float* __restrict__ t2,
                                               const float* __restrict__ w,
                                               const float* __restrict__ bias,
                                               float* __restrict__ out) {
    int p  = blockIdx.x * 256 + threadIdx.x;
    int oc = blockIdx.y;
    int b  = blockIdx.z;
    const float* tb = t2 + (size_t)b * 32 * HW + p;
    const float* wo = w + oc * 32;
    float acc = bias[oc];
    #pragma unroll 8
    for (int c = 0; c < 32; ++c) acc += tb[(size_t)c * HW] * wo[c];
    size_t idx = ((size_t)b * 64 + oc) * HW + p;
    out[idx] = x[idx] + out[idx] + acc;
}

// ---------------------------------------------------------------------------
extern "C" void kernel_launch(void* const* d_in, const int* in_sizes, int n_in,
                              void* d_out, int out_size, void* d_ws, size_t ws_size,
                              hipStream_t stream) {
    const float* x     = (const float*)d_in[0];
    const float* w_off = (const float*)d_in[1];
    const float* b_off = (const float*)d_in[2];
    const float* w_dc  = (const float*)d_in[3];
    const float* b_dc  = (const float*)d_in[4];
    const float* w_ca1 = (const float*)d_in[5];
    const float* b_ca1 = (const float*)d_in[6];
    const float* w_ca2 = (const float*)d_in[7];
    const float* b_ca2 = (const float*)d_in[8];
    const float* w_sa  = (const float*)d_in[9];
    const float* b_sa  = (const float*)d_in[10];
    const float* w_r1  = (const float*)d_in[11];
    const float* b_r1  = (const float*)d_in[12];
    const float* w_r2  = (const float*)d_in[13];
    const float* b_r2  = (const float*)d_in[14];
    const float* w_n1  = (const float*)d_in[15];
    const float* b_n1  = (const float*)d_in[16];
    const float* w_n2  = (const float*)d_in[17];
    const float* b_n2  = (const float*)d_in[18];
    const float* w_n3  = (const float*)d_in[19];
    const float* b_n3  = (const float*)d_in[20];
    float* out = (float*)d_out;

    // ------------------------------------------------------------------
    // Workspace (float offsets). Total 19,150,336 f = 76.6 MB.
    //   A [0,        9437184)  xd fp32; tn2 overlays [0,4718592) after n1.
    //   B [9437184, 14155776)  om fp32 (dead after deform) -> xa bf16.
    //   C [14155776,14303232)  sa fp32
    //   D smalls: ca_in, ca_o, wdct, Apk1, Apk2, Wofpk
    //   E [14431744,19150336)  x_bhwc bf16 (dead after deform) ->
    //                          tr bf16 slab (r-loop) -> tn1 fp32 (n-branch)
    // ------------------------------------------------------------------
    float* ws = (float*)d_ws;
    float* xd    = ws;
    float* om    = ws + 9437184;
    float* sa    = ws + 14155776;
    float* ca_in = ws + 14303232;
    float* ca_o  = ws + 14303488;
    float* wdct  = ws + 14303744;
    unsigned short* Apk1  = (unsigned short*)(ws + 14340608);  // 16384 sh
    unsigned short* Apk2  = (unsigned short*)(ws + 14348800);  // 147456 sh
    unsigned short* Wofpk = (unsigned short*)(ws + 14422528);  // 18432 sh
    float* trE   = ws + 14431744;

    unsigned short* xa_bhwc = (unsigned short*)om;             // 9437184 sh
    unsigned short* x_bhwc  = (unsigned short*)trE;            // 9437184 sh (early)
    unsigned short* trh     = (unsigned short*)trE;            // (mid, after deform)
    float* tn1 = trE;                                          // (late)
    float* tn2 = ws;

    k_x_t     <<<dim3(HW / 64, 4), 256, 0, stream>>>(x, x_bhwc);
    k_wdc_t   <<<144, 256, 0, stream>>>(w_dc, wdct);
    k_prepack <<<712, 256, 0, stream>>>(w_r1, w_r2, w_off, Apk1, Apk2, Wofpk);
    k_off_mfma<<<dim3(3, 192, 4), 256, 0, stream>>>(x_bhwc, Wofpk, b_off, om);
    k_deform  <<<dim3(HW / 32, 4), 256, 0, stream>>>(x_bhwc, om, wdct, b_dc, xd);
    k_camean  <<<256, 256, 0, stream>>>(xd, ca_in);
    k_ca_mlp  <<<1, 256, 0, stream>>>(ca_in, w_ca1, b_ca1, w_ca2, b_ca2, ca_o);
    k_sa      <<<dim3(192, 1, 4), 192, 0, stream>>>(xd, w_sa, b_sa, sa);
    k_scale_t <<<dim3(HW / 64, 4), 256, 0, stream>>>(xd, ca_o, sa, xa_bhwc);

    // r-branch: four 1-batch slabs through the same tr buffer
    for (int b = 0; b < 4; ++b) {
        k_r1_mfma<<<HW / 64, 256, 0, stream>>>(xa_bhwc + (size_t)b * HW * 64,
                                               Apk1, b_r1, trh);
        k_r2_mfma<<<dim3(2, 192), 256, 0, stream>>>(trh, Apk2, b_r2, out, b);
    }

    // n-branch
    k_conv1x1 <<<dim3(144, 32, 4), 256, 0, stream>>>(xd, w_n1, b_n1, tn1, 0, 0);
    k_dw3x3   <<<dim3(192, 32, 4), 192, 0, stream>>>(tn1, w_n2, b_n2, tn2);
    k_final   <<<dim3(144, 64, 4), 256, 0, stream>>>(x, tn2, w_n3, b_n3, out);
}

// Round 6
// 609.296 us; speedup vs baseline: 10.0583x; 1.4552x over previous
//
#include <hip/hip_runtime.h>
#include <hip/hip_bf16.h>
#include <math.h>

#define B_  4
#define C_  64
#define H_  192
#define W_  192
#define HW  36864           // H_*W_
#define CHW 2359296         // C_*HW

typedef __attribute__((ext_vector_type(8))) short short8;
typedef __attribute__((ext_vector_type(4))) float f32x4;

__device__ __forceinline__ float leakyf(float v) { return v >= 0.f ? v : 0.1f * v; }
__device__ __forceinline__ float sigmoidf_(float v) { return 1.f / (1.f + __expf(-v)); }
__device__ __forceinline__ unsigned short f2bf(float f) {
    union { float f; unsigned u; } v; v.f = f;
    unsigned r = v.u + 0x7fff + ((v.u >> 16) & 1);   // round-to-nearest-even
    return (unsigned short)(r >> 16);
}
__device__ __forceinline__ float bf2f(unsigned short s) {
    union { unsigned u; float f; } cv; cv.u = ((unsigned)s) << 16; return cv.f;
}

// ---------------------------------------------------------------------------
// K-1: x (NCHW fp32) -> x_bhwc (NHWC bf16) via LDS transpose
// ---------------------------------------------------------------------------
__global__ __launch_bounds__(256) void k_x_t(const float* __restrict__ x,
                                             unsigned short* __restrict__ xb16) {
    __shared__ unsigned short sT[64 * 72];
    int t  = threadIdx.x;
    int p0 = blockIdx.x * 64;
    int b  = blockIdx.y;
    const float* xb = x + (size_t)b * CHW + p0;
    #pragma unroll
    for (int i = 0; i < 16; ++i) {
        int e = t + i * 256;
        int c = e >> 6, pp = e & 63;
        sT[pp * 72 + c] = f2bf(xb[(size_t)c * HW + pp]);
    }
    __syncthreads();
    unsigned short* xap = xb16 + ((size_t)b * HW + p0) * 64;
    #pragma unroll
    for (int i = 0; i < 2; ++i) {
        int e = t + i * 256;
        int pp = e >> 3, cq = e & 7;
        *(uint4*)(xap + pp * 64 + cq * 8) = *(const uint4*)(sT + pp * 72 + cq * 8);
    }
}

// ---------------------------------------------------------------------------
// K0: prepack all MFMA weights to bf16.
// Apk1  = w_r1  [256][64]
// Apk2  = w_r2  [64 oc][tap*256+c]
// Wofpk = w_off [32 (27 pad)][tap*64+c]
// Wdcb  = w_dc  [k][o][c]
// Wsapk = w_sa  [16 (1 pad)][tap*64+c]
// Wn1pk = w_n1  [32][64]
// 900 blocks x 256 = 230400 threads exactly.
// ---------------------------------------------------------------------------
__global__ void k_prepack(const float* __restrict__ w_r1, const float* __restrict__ w_r2,
                          const float* __restrict__ w_off, const float* __restrict__ w_dc,
                          const float* __restrict__ w_sa, const float* __restrict__ w_n1,
                          unsigned short* __restrict__ Apk1, unsigned short* __restrict__ Apk2,
                          unsigned short* __restrict__ Wofpk, unsigned short* __restrict__ Wdcb,
                          unsigned short* __restrict__ Wsapk, unsigned short* __restrict__ Wn1pk) {
    int t = blockIdx.x * 256 + threadIdx.x;
    if (t < 16384) { Apk1[t] = f2bf(w_r1[t]); return; }
    int e = t - 16384;
    if (e < 147456) {
        int oc = e / 2304, r = e % 2304, tap = r / 256, c = r & 255;
        Apk2[e] = f2bf(w_r2[(oc * 256 + c) * 9 + tap]);
        return;
    }
    e -= 147456;
    if (e < 18432) {
        int m = e / 576, r = e % 576, tap = r / 64, c = r & 63;
        Wofpk[e] = (m < 27) ? f2bf(w_off[m * 576 + c * 9 + tap]) : (unsigned short)0;
        return;
    }
    e -= 18432;
    if (e < 36864) {
        int c = e & 63, r = e >> 6, k = r / 64, o = r & 63;
        Wdcb[e] = f2bf(w_dc[(o * 64 + c) * 9 + k]);
        return;
    }
    e -= 36864;
    if (e < 9216) {
        int m = e / 576, r = e % 576, tap = r / 64, c = r & 63;
        Wsapk[e] = (m == 0) ? f2bf(w_sa[c * 9 + tap]) : (unsigned short)0;
        return;
    }
    e -= 9216;
    if (e < 2048) Wn1pk[e] = f2bf(w_n1[e]);
}

// ---------------------------------------------------------------------------
// K1: offset/mask conv as bf16 implicit-GEMM MFMA. M=32 (27 real oc),
// N=64 x per block, K=9 taps x 64 c. grid = (3, 192, 4).
// ---------------------------------------------------------------------------
__global__ __launch_bounds__(256) void k_off_mfma(const unsigned short* __restrict__ xb16,
                                                  const unsigned short* __restrict__ Wofpk,
                                                  const float* __restrict__ b_off,
                                                  float* __restrict__ om) {
    __shared__ unsigned short sB[3 * 66 * 72];   // 28512 B

    int t    = threadIdx.x;
    int wv   = t >> 6;
    int lane = t & 63;
    int n    = lane & 15;
    int quad = lane >> 4;
    int x0   = blockIdx.x * 64;
    int y    = blockIdx.y;
    int b    = blockIdx.z;
    int xn   = wv * 16;

    #pragma unroll
    for (int i = 0; i < 7; ++i) {
        int e = t + i * 256;
        if (e < 1584) {
            int r   = e / 528;
            int rem = e - r * 528;
            int xi  = rem >> 3;
            int cg  = rem & 7;
            int yy  = y + r - 1;
            int xx  = x0 - 1 + xi;
            uint4 v = make_uint4(0u, 0u, 0u, 0u);
            if (yy >= 0 && yy < H_ && xx >= 0 && xx < W_)
                v = *(const uint4*)(xb16 + ((size_t)b * HW + (size_t)yy * W_ + xx) * 64 + cg * 8);
            *(uint4*)(sB + (r * 66 + xi) * 72 + cg * 8) = v;
        }
    }
    __syncthreads();

    f32x4 acc[2];
    acc[0] = (f32x4){0.f, 0.f, 0.f, 0.f};
    acc[1] = (f32x4){0.f, 0.f, 0.f, 0.f};

    #pragma unroll
    for (int tap = 0; tap < 9; ++tap) {
        int dy = tap / 3, dx = tap % 3;
        #pragma unroll
        for (int kc = 0; kc < 2; ++kc) {
            short8 a0 = *(const short8*)(Wofpk + (size_t)n        * 576 + tap * 64 + kc * 32 + quad * 8);
            short8 a1 = *(const short8*)(Wofpk + (size_t)(16 + n) * 576 + tap * 64 + kc * 32 + quad * 8);
            short8 bf = *(const short8*)(sB + (dy * 66 + xn + n + dx) * 72 + kc * 32 + quad * 8);
            acc[0] = __builtin_amdgcn_mfma_f32_16x16x32_bf16(a0, bf, acc[0], 0, 0, 0);
            acc[1] = __builtin_amdgcn_mfma_f32_16x16x32_bf16(a1, bf, acc[1], 0, 0, 0);
        }
    }

    int xx = x0 + xn + n;
    #pragma unroll
    for (int mt = 0; mt < 2; ++mt) {
        #pragma unroll
        for (int reg = 0; reg < 4; ++reg) {
            int oc = mt * 16 + quad * 4 + reg;
            if (oc < 27) {
                float v = leakyf(acc[mt][reg] + b_off[oc]);
                if (oc >= 18) v = sigmoidf_(v);
                om[((size_t)b * 27 + oc) * HW + (size_t)y * W_ + xx] = v;
            }
        }
    }
}

// ---------------------------------------------------------------------------
// K2: deformable conv, MFMA MAC. Block = 64 pixels, all 64 oc.
// Per k: bilinear-sample val[64p][64c] -> bf16 LDS (pitch 72), then
// GEMM 64o x 64c x 64p with w_dc A-frags direct from L2.
// Output xd in NHWC bf16. grid = (576, 4).
// ---------------------------------------------------------------------------
__global__ __launch_bounds__(256) void k_deform_mfma(const unsigned short* __restrict__ xb16,
                                                     const float* __restrict__ om,
                                                     const unsigned short* __restrict__ Wdcb,
                                                     const float* __restrict__ bias,
                                                     unsigned short* __restrict__ xdb) {
    __shared__ unsigned short val[64 * 72];   // 9216 B
    __shared__ int   sidx[4][64];
    __shared__ float swgt[4][64];

    int t    = threadIdx.x;
    int wv   = t >> 6;
    int lane = t & 63;
    int n    = lane & 15;
    int quad = lane >> 4;
    int b    = blockIdx.y;
    int px0  = blockIdx.x * 64;
    int pp   = t >> 2;            // gather pixel 0..63
    int c0   = (t & 3) * 16;      // gather channel group

    f32x4 acc[4];
    #pragma unroll
    for (int i = 0; i < 4; ++i) acc[i] = (f32x4){0.f, 0.f, 0.f, 0.f};

    const unsigned short* xbh = xb16 + (size_t)b * HW * 64;
    const float* omb = om + (size_t)b * 27 * HW;

    for (int k = 0; k < 9; ++k) {
        __syncthreads();          // protect val/sidx/swgt from prior readers
        if (t < 64) {
            int pix = px0 + t;
            int py_i = pix / W_;
            int px_i = pix - py_i * W_;
            float offy = omb[(size_t)(2 * k)     * HW + pix];
            float offx = omb[(size_t)(2 * k + 1) * HW + pix];
            float m    = omb[(size_t)(18 + k)    * HW + pix];
            float py = (float)py_i + (float)(k / 3 - 1) + offy;
            float px = (float)px_i + (float)(k % 3 - 1) + offx;
            float y0f = floorf(py), x0f = floorf(px);
            float wy = py - y0f, wx = px - x0f;
            int y0 = (int)y0f, x0 = (int)x0f;
            #pragma unroll
            for (int j = 0; j < 4; ++j) {
                int yy = y0 + (j >> 1);
                int xx = x0 + (j & 1);
                bool v = (yy >= 0) && (yy < H_) && (xx >= 0) && (xx < W_);
                int yc = min(max(yy, 0), H_ - 1);
                int xcl = min(max(xx, 0), W_ - 1);
                sidx[j][t] = yc * W_ + xcl;
                float wj = ((j >> 1) ? wy : 1.f - wy) * ((j & 1) ? wx : 1.f - wx);
                swgt[j][t] = v ? wj * m : 0.f;
            }
        }
        __syncthreads();
        // gather + bilinear blend (fp32), convert to bf16 into val
        {
            float vf[16];
            #pragma unroll
            for (int q = 0; q < 16; ++q) vf[q] = 0.f;
            #pragma unroll
            for (int j = 0; j < 4; ++j) {
                float w = swgt[j][pp];
                const unsigned short* src = xbh + (size_t)sidx[j][pp] * 64 + c0;
                short8 s0 = *(const short8*)(src);
                short8 s1 = *(const short8*)(src + 8);
                #pragma unroll
                for (int q = 0; q < 8; ++q) {
                    vf[q]     += w * bf2f((unsigned short)s0[q]);
                    vf[8 + q] += w * bf2f((unsigned short)s1[q]);
                }
            }
            unsigned short pk[16];
            #pragma unroll
            for (int q = 0; q < 16; ++q) pk[q] = f2bf(vf[q]);
            *(uint4*)(val + pp * 72 + c0)     = *(const uint4*)(pk);
            *(uint4*)(val + pp * 72 + c0 + 8) = *(const uint4*)(pk + 8);
        }
        __syncthreads();
        // MFMA: o-tile = wv (16 oc), all 4 p-tiles, K=64
        #pragma unroll
        for (int ks = 0; ks < 2; ++ks) {
            short8 a = *(const short8*)(Wdcb + ((size_t)(k * 64 + wv * 16 + n)) * 64 + ks * 32 + quad * 8);
            #pragma unroll
            for (int pt = 0; pt < 4; ++pt) {
                short8 bf = *(const short8*)(val + (pt * 16 + n) * 72 + ks * 32 + quad * 8);
                acc[pt] = __builtin_amdgcn_mfma_f32_16x16x32_bf16(a, bf, acc[pt], 0, 0, 0);
            }
        }
    }
    // epilogue: D row = oc (quad*4+reg within wave's 16), col = pixel (n)
    int ocb = wv * 16 + quad * 4;
    float b0 = bias[ocb], b1 = bias[ocb + 1], b2 = bias[ocb + 2], b3 = bias[ocb + 3];
    #pragma unroll
    for (int pt = 0; pt < 4; ++pt) {
        int pix = px0 + pt * 16 + n;
        ushort4 pk;
        pk.x = f2bf(acc[pt][0] + b0);
        pk.y = f2bf(acc[pt][1] + b1);
        pk.z = f2bf(acc[pt][2] + b2);
        pk.w = f2bf(acc[pt][3] + b3);
        *(ushort4*)(xdb + ((size_t)b * HW + pix) * 64 + ocb) = pk;
    }
}

// ---------------------------------------------------------------------------
// K3a: per-(b,c) partial spatial sums of xd (NHWC bf16), 1024 px per block.
// grid = (36, 4). Coalesced: wave lanes cover 64 consecutive c.
// ---------------------------------------------------------------------------
__global__ __launch_bounds__(256) void k_camean(const unsigned short* __restrict__ xdb,
                                                float* __restrict__ ca_part) {
    int t = threadIdx.x;
    int chunk = blockIdx.x;
    int b = blockIdx.y;
    int c = t & 63, sub = t >> 6;
    const unsigned short* base = xdb + ((size_t)b * HW + chunk * 1024 + sub * 256) * 64 + c;
    float s = 0.f;
    for (int i = 0; i < 256; ++i) s += bf2f(base[(size_t)i * 64]);
    __shared__ float sm[256];
    sm[t] = s;
    __syncthreads();
    if (t < 64)
        ca_part[((size_t)b * 36 + chunk) * 64 + t] = sm[t] + sm[64 + t] + sm[128 + t] + sm[192 + t];
}

// ---------------------------------------------------------------------------
// K3b: reduce partials + tiny MLP 64->8(relu)->64(sigmoid), one block.
// ---------------------------------------------------------------------------
__global__ __launch_bounds__(256) void k_ca_mlp(const float* __restrict__ ca_part,
                                                const float* __restrict__ w1,
                                                const float* __restrict__ b1,
                                                const float* __restrict__ w2,
                                                const float* __restrict__ b2,
                                                float* __restrict__ ca_out) {
    __shared__ float cain[256];
    __shared__ float h[32];
    int t = threadIdx.x;
    {
        int b = t >> 6, c = t & 63;
        float s = 0.f;
        #pragma unroll
        for (int j = 0; j < 36; ++j) s += ca_part[((size_t)b * 36 + j) * 64 + c];
        cain[t] = s * (1.f / (float)HW);
    }
    __syncthreads();
    if (t < 32) {
        int b = t >> 3, j = t & 7;
        float a = b1[j];
        for (int c = 0; c < 64; ++c) a += w1[j * 64 + c] * cain[b * 64 + c];
        h[t] = a > 0.f ? a : 0.f;
    }
    __syncthreads();
    int b = t >> 6, c = t & 63;
    float a = b2[c];
    #pragma unroll
    for (int j = 0; j < 8; ++j) a += w2[c * 8 + j] * h[b * 8 + j];
    ca_out[t] = sigmoidf_(a);
}

// ---------------------------------------------------------------------------
// K4: spatial attention 3x3 conv 64->1 + sigmoid, MFMA M=16 (1 real row).
// grid = (3, 192, 4). Same staging as k_off_mfma but from xd NHWC bf16.
// ---------------------------------------------------------------------------
__global__ __launch_bounds__(256) void k_sa_mfma(const unsigned short* __restrict__ xdb,
                                                 const unsigned short* __restrict__ Wsapk,
                                                 const float* __restrict__ b_sa,
                                                 float* __restrict__ sa) {
    __shared__ unsigned short sB[3 * 66 * 72];

    int t    = threadIdx.x;
    int wv   = t >> 6;
    int lane = t & 63;
    int n    = lane & 15;
    int quad = lane >> 4;
    int x0   = blockIdx.x * 64;
    int y    = blockIdx.y;
    int b    = blockIdx.z;
    int xn   = wv * 16;

    #pragma unroll
    for (int i = 0; i < 7; ++i) {
        int e = t + i * 256;
        if (e < 1584) {
            int r   = e / 528;
            int rem = e - r * 528;
            int xi  = rem >> 3;
            int cg  = rem & 7;
            int yy  = y + r - 1;
            int xx  = x0 - 1 + xi;
            uint4 v = make_uint4(0u, 0u, 0u, 0u);
            if (yy >= 0 && yy < H_ && xx >= 0 && xx < W_)
                v = *(const uint4*)(xdb + ((size_t)b * HW + (size_t)yy * W_ + xx) * 64 + cg * 8);
            *(uint4*)(sB + (r * 66 + xi) * 72 + cg * 8) = v;
        }
    }
    __syncthreads();

    f32x4 acc = (f32x4){0.f, 0.f, 0.f, 0.f};
    #pragma unroll
    for (int tap = 0; tap < 9; ++tap) {
        int dy = tap / 3, dx = tap % 3;
        #pragma unroll
        for (int kc = 0; kc < 2; ++kc) {
            short8 a  = *(const short8*)(Wsapk + (size_t)n * 576 + tap * 64 + kc * 32 + quad * 8);
            short8 bf = *(const short8*)(sB + (dy * 66 + xn + n + dx) * 72 + kc * 32 + quad * 8);
            acc = __builtin_amdgcn_mfma_f32_16x16x32_bf16(a, bf, acc, 0, 0, 0);
        }
    }
    if (quad == 0)   // row 0 = the real output channel
        sa[(size_t)b * HW + (size_t)y * W_ + x0 + xn + n] = sigmoidf_(acc[0] + b_sa[0]);
}

// ---------------------------------------------------------------------------
// K5: xa = xd * (ca + sa), NHWC bf16 -> NHWC bf16, pure elementwise.
// grid = 4608 x 256 threads, one uint4 (8 ch) per thread.
// ---------------------------------------------------------------------------
__global__ __launch_bounds__(256) void k_scale(const unsigned short* __restrict__ xdb,
                                               const float* __restrict__ ca,
                                               const float* __restrict__ sa,
                                               unsigned short* __restrict__ xa) {
    int idx = blockIdx.x * 256 + threadIdx.x;   // uint4 units
    int pg  = idx >> 3;                          // global pixel (b*HW+p)
    int c0  = (idx & 7) * 8;
    int b   = pg / HW;
    int p   = pg - b * HW;
    float sv = sa[(size_t)b * HW + p];
    uint4 v = *(const uint4*)(xdb + (size_t)idx * 8);
    unsigned short* sp = (unsigned short*)&v;
    unsigned short pk[8];
    #pragma unroll
    for (int q = 0; q < 8; ++q)
        pk[q] = f2bf(bf2f(sp[q]) * (ca[b * 64 + c0 + q] + sv));
    *(uint4*)(xa + (size_t)idx * 8) = *(const uint4*)pk;
}

// ---------------------------------------------------------------------------
// K6: r1 = leaky(1x1 conv 64->256) bf16 MFMA GEMM, per 1-batch slab.
// ---------------------------------------------------------------------------
__global__ __launch_bounds__(256) void k_r1_mfma(const unsigned short* __restrict__ xa_s,
                                                 const unsigned short* __restrict__ Apk1,
                                                 const float* __restrict__ b_r1,
                                                 unsigned short* __restrict__ tr) {
    int t    = threadIdx.x;
    int wv   = t >> 6;
    int lane = t & 63;
    int n    = lane & 15;
    int quad = lane >> 4;
    size_t p0 = (size_t)blockIdx.x * 64;

    f32x4 acc[4][4];
    #pragma unroll
    for (int i = 0; i < 4; ++i)
        #pragma unroll
        for (int j = 0; j < 4; ++j) acc[i][j] = (f32x4){0.f, 0.f, 0.f, 0.f};

    #pragma unroll
    for (int ks = 0; ks < 2; ++ks) {
        int k0 = ks * 32;
        short8 bfrag[4];
        #pragma unroll
        for (int jt = 0; jt < 4; ++jt)
            bfrag[jt] = *(const short8*)(xa_s + (p0 + jt * 16 + n) * 64 + k0 + quad * 8);
        #pragma unroll
        for (int mt = 0; mt < 4; ++mt) {
            short8 afrag = *(const short8*)(Apk1 + (wv * 64 + mt * 16 + n) * 64 + k0 + quad * 8);
            #pragma unroll
            for (int jt = 0; jt < 4; ++jt)
                acc[mt][jt] = __builtin_amdgcn_mfma_f32_16x16x32_bf16(afrag, bfrag[jt], acc[mt][jt], 0, 0, 0);
        }
    }
    #pragma unroll
    for (int mt = 0; mt < 4; ++mt) {
        int ocb = wv * 64 + mt * 16 + quad * 4;
        float b0 = b_r1[ocb], b1 = b_r1[ocb + 1], b2 = b_r1[ocb + 2], b3 = b_r1[ocb + 3];
        #pragma unroll
        for (int jt = 0; jt < 4; ++jt) {
            size_t p = p0 + jt * 16 + n;
            ushort4 pk;
            pk.x = f2bf(leakyf(acc[mt][jt][0] + b0));
            pk.y = f2bf(leakyf(acc[mt][jt][1] + b1));
            pk.z = f2bf(leakyf(acc[mt][jt][2] + b2));
            pk.w = f2bf(leakyf(acc[mt][jt][3] + b3));
            *(ushort4*)(tr + p * 256 + ocb) = pk;
        }
    }
}

// ---------------------------------------------------------------------------
// K7: r2 = 3x3 conv 256->64 bf16 MFMA, per 1-batch slab, half-row blocks.
// ---------------------------------------------------------------------------
#define R2P 40
__global__ __launch_bounds__(256) void k_r2_mfma(const unsigned short* __restrict__ tr,
                                                 const unsigned short* __restrict__ Apk2,
                                                 const float* __restrict__ b_r2,
                                                 float* __restrict__ out,
                                                 int b_glob) {
    __shared__ unsigned short sB[3 * 98 * R2P];   // 23520 B

    int t     = threadIdx.x;
    int wv    = t >> 6;
    int lane  = t & 63;
    int n     = lane & 15;
    int quad  = lane >> 4;
    int xh    = blockIdx.x;
    int y     = blockIdx.y;
    int x0    = xh * 96;
    int mbase = (wv & 1) * 32;
    int xbase = (wv >> 1) * 48;

    f32x4 acc[2][3];
    #pragma unroll
    for (int i = 0; i < 2; ++i)
        #pragma unroll
        for (int j = 0; j < 3; ++j) acc[i][j] = (f32x4){0.f, 0.f, 0.f, 0.f};

    for (int c0 = 0; c0 < 256; c0 += 32) {
        __syncthreads();
        #pragma unroll
        for (int i = 0; i < 5; ++i) {
            int e = t + i * 256;
            if (e < 1176) {
                int r   = e / 392;
                int rem = e - r * 392;
                int xi  = rem >> 2;
                int cq  = rem & 3;
                int yy  = y + r - 1;
                int xx  = x0 - 1 + xi;
                uint4 v = make_uint4(0u, 0u, 0u, 0u);
                if (yy >= 0 && yy < H_ && xx >= 0 && xx < W_)
                    v = *(const uint4*)(tr + ((size_t)yy * W_ + xx) * 256 + c0 + cq * 8);
                *(uint4*)(sB + (r * 98 + xi) * R2P + cq * 8) = v;
            }
        }
        __syncthreads();
        #pragma unroll
        for (int tap = 0; tap < 9; ++tap) {
            int dy = tap / 3, dx = tap % 3;
            short8 a0 = *(const short8*)(Apk2 + (size_t)(mbase + n)      * 2304 + tap * 256 + c0 + quad * 8);
            short8 a1 = *(const short8*)(Apk2 + (size_t)(mbase + 16 + n) * 2304 + tap * 256 + c0 + quad * 8);
            #pragma unroll
            for (int j = 0; j < 3; ++j) {
                int xi = xbase + j * 16 + n + dx;
                short8 bf = *(const short8*)(sB + (dy * 98 + xi) * R2P + quad * 8);
                acc[0][j] = __builtin_amdgcn_mfma_f32_16x16x32_bf16(a0, bf, acc[0][j], 0, 0, 0);
                acc[1][j] = __builtin_amdgcn_mfma_f32_16x16x32_bf16(a1, bf, acc[1][j], 0, 0, 0);
            }
        }
    }
    #pragma unroll
    for (int mt = 0; mt < 2; ++mt) {
        int oc = mbase + mt * 16 + quad * 4;
        float b0 = b_r2[oc], b1 = b_r2[oc + 1], b2 = b_r2[oc + 2], b3 = b_r2[oc + 3];
        #pragma unroll
        for (int j = 0; j < 3; ++j) {
            int xx = x0 + xbase + j * 16 + n;
            float* op = out + ((size_t)b_glob * 64 + oc) * HW + y * W_ + xx;
            op[0]              = acc[mt][j][0] + b0;
            op[HW]             = acc[mt][j][1] + b1;
            op[2 * HW]         = acc[mt][j][2] + b2;
            op[3 * (size_t)HW] = acc[mt][j][3] + b3;
        }
    }
}

// ---------------------------------------------------------------------------
// K8: n1 = 1x1 conv 64->32 bf16 MFMA, out tn1 NCHW fp32. grid (576, 4).
// ---------------------------------------------------------------------------
__global__ __launch_bounds__(256) void k_n1_mfma(const unsigned short* __restrict__ xa,
                                                 const unsigned short* __restrict__ Wn1pk,
                                                 const float* __restrict__ b_n1,
                                                 float* __restrict__ tn1) {
    int t    = threadIdx.x;
    int wv   = t >> 6;
    int lane = t & 63;
    int n    = lane & 15;
    int quad = lane >> 4;
    int b    = blockIdx.y;
    int pix  = blockIdx.x * 64 + wv * 16 + n;

    f32x4 acc[2];
    acc[0] = (f32x4){0.f, 0.f, 0.f, 0.f};
    acc[1] = (f32x4){0.f, 0.f, 0.f, 0.f};

    #pragma unroll
    for (int ks = 0; ks < 2; ++ks) {
        short8 bf = *(const short8*)(xa + ((size_t)b * HW + pix) * 64 + ks * 32 + quad * 8);
        #pragma unroll
        for (int mt = 0; mt < 2; ++mt) {
            short8 a = *(const short8*)(Wn1pk + (size_t)(mt * 16 + n) * 64 + ks * 32 + quad * 8);
            acc[mt] = __builtin_amdgcn_mfma_f32_16x16x32_bf16(a, bf, acc[mt], 0, 0, 0);
        }
    }
    #pragma unroll
    for (int mt = 0; mt < 2; ++mt) {
        #pragma unroll
        for (int reg = 0; reg < 4; ++reg) {
            int oc = mt * 16 + quad * 4 + reg;
            tn1[((size_t)b * 32 + oc) * HW + pix] = acc[mt][reg] + b_n1[oc];
        }
    }
}

// ---------------------------------------------------------------------------
// K9: depthwise 3x3, 32 channels, fp32 NCHW (unchanged)
// ---------------------------------------------------------------------------
__global__ __launch_bounds__(192) void k_dw3x3(const float* __restrict__ t1,
                                               const float* __restrict__ w,
                                               const float* __restrict__ bias,
                                               float* __restrict__ t2) {
    int xc = threadIdx.x;
    int y  = blockIdx.x;
    int c  = blockIdx.y;
    int b  = blockIdx.z;
    const float* src = t1 + ((size_t)b * 32 + c) * HW;
    const float* wc  = w + c * 9;
    float acc = bias[c];
    #pragma unroll
    for (int dy = -1; dy <= 1; ++dy) {
        int yy = y + dy;
        if (yy < 0 || yy >= H_) continue;
        const float* row = src + yy * W_;
        #pragma unroll
        for (int dx = -1; dx <= 1; ++dx) {
            int xx = xc + dx;
            float v = (xx >= 0 && xx < W_) ? row[xx] : 0.f;
            acc += v * wc[(dy + 1) * 3 + (dx + 1)];
        }
    }
    t2[((size_t)b * 32 + c) * HW + y * W_ + xc] = acc;
}

// ---------------------------------------------------------------------------
// K10: out = x + xr(in d_out) + (w_n3 @ t2 + b_n3)
// ---------------------------------------------------------------------------
__global__ __launch_bounds__(256) void k_final(const float* __restrict__ x,
                                               const float* __restrict__ t2,
                                               const float* __restrict__ w,
                                               const float* __restrict__ bias,
                                               float* __restrict__ out) {
    int p  = blockIdx.x * 256 + threadIdx.x;
    int oc = blockIdx.y;
    int b  = blockIdx.z;
    const float* tb = t2 + (size_t)b * 32 * HW + p;
    const float* wo = w + oc * 32;
    float acc = bias[oc];
    #pragma unroll 8
    for (int c = 0; c < 32; ++c) acc += tb[(size_t)c * HW] * wo[c];
    size_t idx = ((size_t)b * 64 + oc) * HW + p;
    out[idx] = x[idx] + out[idx] + acc;
}

// ---------------------------------------------------------------------------
extern "C" void kernel_launch(void* const* d_in, const int* in_sizes, int n_in,
                              void* d_out, int out_size, void* d_ws, size_t ws_size,
                              hipStream_t stream) {
    const float* x     = (const float*)d_in[0];
    const float* w_off = (const float*)d_in[1];
    const float* b_off = (const float*)d_in[2];
    const float* w_dc  = (const float*)d_in[3];
    const float* b_dc  = (const float*)d_in[4];
    const float* w_ca1 = (const float*)d_in[5];
    const float* b_ca1 = (const float*)d_in[6];
    const float* w_ca2 = (const float*)d_in[7];
    const float* b_ca2 = (const float*)d_in[8];
    const float* w_sa  = (const float*)d_in[9];
    const float* b_sa  = (const float*)d_in[10];
    const float* w_r1  = (const float*)d_in[11];
    const float* b_r1  = (const float*)d_in[12];
    const float* w_r2  = (const float*)d_in[13];
    const float* b_r2  = (const float*)d_in[14];
    const float* w_n1  = (const float*)d_in[15];
    const float* b_n1  = (const float*)d_in[16];
    const float* w_n2  = (const float*)d_in[17];
    const float* b_n2  = (const float*)d_in[18];
    const float* w_n3  = (const float*)d_in[19];
    const float* b_n3  = (const float*)d_in[20];
    float* out = (float*)d_out;

    // ------------------------------------------------------------------
    // Workspace (float offsets). Total 18,409,216 f = 73.6 MB (< 76.6 proven).
    //  A [0,        4718592)  xd NHWC bf16 (deform -> scale); then tn1 fp32.
    //  B [4718592,  9437184)  xa NHWC bf16 (scale -> r1 x4, n1); then tn2 fp32.
    //  C [9437184, 13418496)  om fp32 (off -> deform).
    //  D [13418496,13565952)  sa fp32.
    //  E [13565952,13690624)  ca_part, ca_o, prepacked bf16 weights.
    //  F [13690624,18409216)  x NHWC bf16 (x_t -> deform); then tr bf16 slab.
    // ------------------------------------------------------------------
    float* ws = (float*)d_ws;
    unsigned short* xd_bhwc = (unsigned short*)ws;                    // A
    unsigned short* xa_bhwc = (unsigned short*)(ws + 4718592);        // B
    float* om      = ws + 9437184;                                    // C
    float* sa      = ws + 13418496;                                   // D
    float* ca_part = ws + 13565952;                                   // 9216 f
    float* ca_o    = ws + 13575168;                                   // 256 f
    unsigned short* Apk1  = (unsigned short*)(ws + 13575424);         // 16384 sh
    unsigned short* Apk2  = Apk1 + 16384;                             // 147456 sh
    unsigned short* Wofpk = Apk2 + 147456;                            // 18432 sh
    unsigned short* Wdcb  = Wofpk + 18432;                            // 36864 sh
    unsigned short* Wsapk = Wdcb + 36864;                             // 9216 sh
    unsigned short* Wn1pk = Wsapk + 9216;                             // 2048 sh
    unsigned short* x_bhwc = (unsigned short*)(ws + 13690624);        // F
    unsigned short* trh    = x_bhwc;                                  // F (after deform)
    float* tn1 = (float*)xd_bhwc;                                     // A (after scale)
    float* tn2 = (float*)xa_bhwc;                                     // B (after n1)

    k_x_t        <<<dim3(HW / 64, 4), 256, 0, stream>>>(x, x_bhwc);
    k_prepack    <<<900, 256, 0, stream>>>(w_r1, w_r2, w_off, w_dc, w_sa, w_n1,
                                           Apk1, Apk2, Wofpk, Wdcb, Wsapk, Wn1pk);
    k_off_mfma   <<<dim3(3, 192, 4), 256, 0, stream>>>(x_bhwc, Wofpk, b_off, om);
    k_deform_mfma<<<dim3(576, 4), 256, 0, stream>>>(x_bhwc, om, Wdcb, b_dc, xd_bhwc);
    k_camean     <<<dim3(36, 4), 256, 0, stream>>>(xd_bhwc, ca_part);
    k_ca_mlp     <<<1, 256, 0, stream>>>(ca_part, w_ca1, b_ca1, w_ca2, b_ca2, ca_o);
    k_sa_mfma    <<<dim3(3, 192, 4), 256, 0, stream>>>(xd_bhwc, Wsapk, b_sa, sa);
    k_scale      <<<4608, 256, 0, stream>>>(xd_bhwc, ca_o, sa, xa_bhwc);

    // r-branch: four 1-batch slabs through tr (stream-serialized)
    for (int b = 0; b < 4; ++b) {
        k_r1_mfma<<<HW / 64, 256, 0, stream>>>(xa_bhwc + (size_t)b * HW * 64,
                                               Apk1, b_r1, trh);
        k_r2_mfma<<<dim3(2, 192), 256, 0, stream>>>(trh, Apk2, b_r2, out, b);
    }

    // n-branch
    k_n1_mfma<<<dim3(576, 4), 256, 0, stream>>>(xa_bhwc, Wn1pk, b_n1, tn1);
    k_dw3x3  <<<dim3(192, 32, 4), 192, 0, stream>>>(tn1, w_n2, b_n2, tn2);
    k_final  <<<dim3(144, 64, 4), 256, 0, stream>>>(x, tn2, w_n3, b_n3, out);
}

// Round 7
// 596.688 us; speedup vs baseline: 10.2708x; 1.0211x over previous
//
#include <hip/hip_runtime.h>
#include <hip/hip_bf16.h>
#include <math.h>

#define B_  4
#define C_  64
#define H_  192
#define W_  192
#define HW  36864           // H_*W_
#define CHW 2359296         // C_*HW

typedef __attribute__((ext_vector_type(8))) short short8;
typedef __attribute__((ext_vector_type(4))) float f32x4;

__device__ __forceinline__ float leakyf(float v) { return v >= 0.f ? v : 0.1f * v; }
__device__ __forceinline__ float sigmoidf_(float v) { return 1.f / (1.f + __expf(-v)); }
__device__ __forceinline__ unsigned short f2bf(float f) {
    union { float f; unsigned u; } v; v.f = f;
    unsigned r = v.u + 0x7fff + ((v.u >> 16) & 1);   // round-to-nearest-even
    return (unsigned short)(r >> 16);
}
__device__ __forceinline__ float bf2f(unsigned short s) {
    union { unsigned u; float f; } cv; cv.u = ((unsigned)s) << 16; return cv.f;
}

// ---------------------------------------------------------------------------
// K-1: x (NCHW fp32) -> x_bhwc (NHWC bf16) via LDS transpose
// ---------------------------------------------------------------------------
__global__ __launch_bounds__(256) void k_x_t(const float* __restrict__ x,
                                             unsigned short* __restrict__ xb16) {
    __shared__ unsigned short sT[64 * 72];
    int t  = threadIdx.x;
    int p0 = blockIdx.x * 64;
    int b  = blockIdx.y;
    const float* xb = x + (size_t)b * CHW + p0;
    #pragma unroll
    for (int i = 0; i < 16; ++i) {
        int e = t + i * 256;
        int c = e >> 6, pp = e & 63;
        sT[pp * 72 + c] = f2bf(xb[(size_t)c * HW + pp]);
    }
    __syncthreads();
    unsigned short* xap = xb16 + ((size_t)b * HW + p0) * 64;
    #pragma unroll
    for (int i = 0; i < 2; ++i) {
        int e = t + i * 256;
        int pp = e >> 3, cq = e & 7;
        *(uint4*)(xap + pp * 64 + cq * 8) = *(const uint4*)(sT + pp * 72 + cq * 8);
    }
}

// ---------------------------------------------------------------------------
// K0: prepack all MFMA weights to bf16. 908 blocks x 256 covers 232448 items.
// ---------------------------------------------------------------------------
__global__ void k_prepack(const float* __restrict__ w_r1, const float* __restrict__ w_r2,
                          const float* __restrict__ w_off, const float* __restrict__ w_dc,
                          const float* __restrict__ w_sa, const float* __restrict__ w_n1,
                          const float* __restrict__ w_n3,
                          unsigned short* __restrict__ Apk1, unsigned short* __restrict__ Apk2,
                          unsigned short* __restrict__ Wofpk, unsigned short* __restrict__ Wdcb,
                          unsigned short* __restrict__ Wsapk, unsigned short* __restrict__ Wn1pk,
                          unsigned short* __restrict__ Wn3pk) {
    int t = blockIdx.x * 256 + threadIdx.x;
    if (t < 16384) { Apk1[t] = f2bf(w_r1[t]); return; }
    int e = t - 16384;
    if (e < 147456) {
        int oc = e / 2304, r = e % 2304, tap = r / 256, c = r & 255;
        Apk2[e] = f2bf(w_r2[(oc * 256 + c) * 9 + tap]);
        return;
    }
    e -= 147456;
    if (e < 18432) {
        int m = e / 576, r = e % 576, tap = r / 64, c = r & 63;
        Wofpk[e] = (m < 27) ? f2bf(w_off[m * 576 + c * 9 + tap]) : (unsigned short)0;
        return;
    }
    e -= 18432;
    if (e < 36864) {
        int c = e & 63, r = e >> 6, k = r / 64, o = r & 63;
        Wdcb[e] = f2bf(w_dc[(o * 64 + c) * 9 + k]);
        return;
    }
    e -= 36864;
    if (e < 9216) {
        int m = e / 576, r = e % 576, tap = r / 64, c = r & 63;
        Wsapk[e] = (m == 0) ? f2bf(w_sa[c * 9 + tap]) : (unsigned short)0;
        return;
    }
    e -= 9216;
    if (e < 2048) { Wn1pk[e] = f2bf(w_n1[e]); return; }
    e -= 2048;
    if (e < 2048) Wn3pk[e] = f2bf(w_n3[e]);
}

// ---------------------------------------------------------------------------
// K1: offset/mask conv bf16 MFMA; output om in bf16. grid = (3, 192, 4).
// ---------------------------------------------------------------------------
__global__ __launch_bounds__(256) void k_off_mfma(const unsigned short* __restrict__ xb16,
                                                  const unsigned short* __restrict__ Wofpk,
                                                  const float* __restrict__ b_off,
                                                  unsigned short* __restrict__ om) {
    __shared__ unsigned short sB[3 * 66 * 72];   // 28512 B

    int t    = threadIdx.x;
    int wv   = t >> 6;
    int lane = t & 63;
    int n    = lane & 15;
    int quad = lane >> 4;
    int x0   = blockIdx.x * 64;
    int y    = blockIdx.y;
    int b    = blockIdx.z;
    int xn   = wv * 16;

    #pragma unroll
    for (int i = 0; i < 7; ++i) {
        int e = t + i * 256;
        if (e < 1584) {
            int r   = e / 528;
            int rem = e - r * 528;
            int xi  = rem >> 3;
            int cg  = rem & 7;
            int yy  = y + r - 1;
            int xx  = x0 - 1 + xi;
            uint4 v = make_uint4(0u, 0u, 0u, 0u);
            if (yy >= 0 && yy < H_ && xx >= 0 && xx < W_)
                v = *(const uint4*)(xb16 + ((size_t)b * HW + (size_t)yy * W_ + xx) * 64 + cg * 8);
            *(uint4*)(sB + (r * 66 + xi) * 72 + cg * 8) = v;
        }
    }
    __syncthreads();

    f32x4 acc[2];
    acc[0] = (f32x4){0.f, 0.f, 0.f, 0.f};
    acc[1] = (f32x4){0.f, 0.f, 0.f, 0.f};

    #pragma unroll
    for (int tap = 0; tap < 9; ++tap) {
        int dy = tap / 3, dx = tap % 3;
        #pragma unroll
        for (int kc = 0; kc < 2; ++kc) {
            short8 a0 = *(const short8*)(Wofpk + (size_t)n        * 576 + tap * 64 + kc * 32 + quad * 8);
            short8 a1 = *(const short8*)(Wofpk + (size_t)(16 + n) * 576 + tap * 64 + kc * 32 + quad * 8);
            short8 bf = *(const short8*)(sB + (dy * 66 + xn + n + dx) * 72 + kc * 32 + quad * 8);
            acc[0] = __builtin_amdgcn_mfma_f32_16x16x32_bf16(a0, bf, acc[0], 0, 0, 0);
            acc[1] = __builtin_amdgcn_mfma_f32_16x16x32_bf16(a1, bf, acc[1], 0, 0, 0);
        }
    }

    int xx = x0 + xn + n;
    #pragma unroll
    for (int mt = 0; mt < 2; ++mt) {
        #pragma unroll
        for (int reg = 0; reg < 4; ++reg) {
            int oc = mt * 16 + quad * 4 + reg;
            if (oc < 27) {
                float v = leakyf(acc[mt][reg] + b_off[oc]);
                if (oc >= 18) v = sigmoidf_(v);
                om[((size_t)b * 27 + oc) * HW + (size_t)y * W_ + xx] = f2bf(v);
            }
        }
    }
}

// ---------------------------------------------------------------------------
// K2: deformable conv, register-direct MFMA. Wave = 16 pixels x 64 oc.
// No LDS, no __syncthreads. Each lane gathers/blends its own B-fragment
// channels (quad*8, 32+quad*8); A-frags from L2. grid = (576, 4).
// ---------------------------------------------------------------------------
__global__ __launch_bounds__(256) void k_deform_mfma(const unsigned short* __restrict__ xb16,
                                                     const unsigned short* __restrict__ om,
                                                     const unsigned short* __restrict__ Wdcb,
                                                     const float* __restrict__ bias,
                                                     unsigned short* __restrict__ xdb) {
    int t    = threadIdx.x;
    int wv   = t >> 6;
    int lane = t & 63;
    int n    = lane & 15;
    int quad = lane >> 4;
    int b    = blockIdx.y;
    int pix  = blockIdx.x * 64 + wv * 16 + n;
    int py_i = pix / W_;
    int px_i = pix - py_i * W_;

    f32x4 acc[4];
    #pragma unroll
    for (int i = 0; i < 4; ++i) acc[i] = (f32x4){0.f, 0.f, 0.f, 0.f};

    const unsigned short* xbh = xb16 + (size_t)b * HW * 64 + quad * 8;
    const unsigned short* omb = om + (size_t)b * 27 * HW;

    #pragma unroll
    for (int k = 0; k < 9; ++k) {
        float offy = bf2f(omb[(size_t)(2 * k)     * HW + pix]);
        float offx = bf2f(omb[(size_t)(2 * k + 1) * HW + pix]);
        float m    = bf2f(omb[(size_t)(18 + k)    * HW + pix]);
        float py = (float)py_i + (float)(k / 3 - 1) + offy;
        float px = (float)px_i + (float)(k % 3 - 1) + offx;
        float y0f = floorf(py), x0f = floorf(px);
        float wy = py - y0f, wx = px - x0f;
        int y0 = (int)y0f, x0 = (int)x0f;

        float vf[16];
        #pragma unroll
        for (int q = 0; q < 16; ++q) vf[q] = 0.f;
        #pragma unroll
        for (int j = 0; j < 4; ++j) {
            int yy = y0 + (j >> 1);
            int xx = x0 + (j & 1);
            bool vd = (yy >= 0) && (yy < H_) && (xx >= 0) && (xx < W_);
            int yc  = min(max(yy, 0), H_ - 1);
            int xcl = min(max(xx, 0), W_ - 1);
            float w = ((j >> 1) ? wy : 1.f - wy) * ((j & 1) ? wx : 1.f - wx);
            w = vd ? w * m : 0.f;
            const unsigned short* src = xbh + (size_t)(yc * W_ + xcl) * 64;
            short8 s0 = *(const short8*)(src);
            short8 s1 = *(const short8*)(src + 32);
            #pragma unroll
            for (int q = 0; q < 8; ++q) {
                vf[q]     += w * bf2f((unsigned short)s0[q]);
                vf[8 + q] += w * bf2f((unsigned short)s1[q]);
            }
        }
        unsigned short pk[16];
        #pragma unroll
        for (int q = 0; q < 16; ++q) pk[q] = f2bf(vf[q]);
        short8 frag0 = *(const short8*)(pk);
        short8 frag1 = *(const short8*)(pk + 8);

        const unsigned short* wk = Wdcb + (size_t)k * 64 * 64 + quad * 8;
        #pragma unroll
        for (int ot = 0; ot < 4; ++ot) {
            short8 a0 = *(const short8*)(wk + (size_t)(ot * 16 + n) * 64);
            short8 a1 = *(const short8*)(wk + (size_t)(ot * 16 + n) * 64 + 32);
            acc[ot] = __builtin_amdgcn_mfma_f32_16x16x32_bf16(a0, frag0, acc[ot], 0, 0, 0);
            acc[ot] = __builtin_amdgcn_mfma_f32_16x16x32_bf16(a1, frag1, acc[ot], 0, 0, 0);
        }
    }
    #pragma unroll
    for (int ot = 0; ot < 4; ++ot) {
        int oc = ot * 16 + quad * 4;
        ushort4 pk;
        pk.x = f2bf(acc[ot][0] + bias[oc]);
        pk.y = f2bf(acc[ot][1] + bias[oc + 1]);
        pk.z = f2bf(acc[ot][2] + bias[oc + 2]);
        pk.w = f2bf(acc[ot][3] + bias[oc + 3]);
        *(ushort4*)(xdb + ((size_t)b * HW + pix) * 64 + oc) = pk;
    }
}

// ---------------------------------------------------------------------------
// K3a: per-(b,c) partial spatial sums of xd (NHWC bf16). grid = (36, 4).
// ---------------------------------------------------------------------------
__global__ __launch_bounds__(256) void k_camean(const unsigned short* __restrict__ xdb,
                                                float* __restrict__ ca_part) {
    int t = threadIdx.x;
    int chunk = blockIdx.x;
    int b = blockIdx.y;
    int c = t & 63, sub = t >> 6;
    const unsigned short* base = xdb + ((size_t)b * HW + chunk * 1024 + sub * 256) * 64 + c;
    float s = 0.f;
    for (int i = 0; i < 256; ++i) s += bf2f(base[(size_t)i * 64]);
    __shared__ float sm[256];
    sm[t] = s;
    __syncthreads();
    if (t < 64)
        ca_part[((size_t)b * 36 + chunk) * 64 + t] = sm[t] + sm[64 + t] + sm[128 + t] + sm[192 + t];
}

// ---------------------------------------------------------------------------
// K3b: reduce partials + tiny MLP 64->8(relu)->64(sigmoid), one block.
// ---------------------------------------------------------------------------
__global__ __launch_bounds__(256) void k_ca_mlp(const float* __restrict__ ca_part,
                                                const float* __restrict__ w1,
                                                const float* __restrict__ b1,
                                                const float* __restrict__ w2,
                                                const float* __restrict__ b2,
                                                float* __restrict__ ca_out) {
    __shared__ float cain[256];
    __shared__ float h[32];
    int t = threadIdx.x;
    {
        int b = t >> 6, c = t & 63;
        float s = 0.f;
        #pragma unroll
        for (int j = 0; j < 36; ++j) s += ca_part[((size_t)b * 36 + j) * 64 + c];
        cain[t] = s * (1.f / (float)HW);
    }
    __syncthreads();
    if (t < 32) {
        int b = t >> 3, j = t & 7;
        float a = b1[j];
        for (int c = 0; c < 64; ++c) a += w1[j * 64 + c] * cain[b * 64 + c];
        h[t] = a > 0.f ? a : 0.f;
    }
    __syncthreads();
    int b = t >> 6, c = t & 63;
    float a = b2[c];
    #pragma unroll
    for (int j = 0; j < 8; ++j) a += w2[c * 8 + j] * h[b * 8 + j];
    ca_out[t] = sigmoidf_(a);
}

// ---------------------------------------------------------------------------
// K4: FUSED spatial attention + scale. MFMA 3x3 conv 64->1 + sigmoid, then
// xa = xd * (ca + sa) from the already-staged center row in sB.
// grid = (3, 192, 4).
// ---------------------------------------------------------------------------
__global__ __launch_bounds__(256) void k_sa_scale(const unsigned short* __restrict__ xdb,
                                                  const unsigned short* __restrict__ Wsapk,
                                                  const float* __restrict__ b_sa,
                                                  const float* __restrict__ ca,
                                                  unsigned short* __restrict__ xa) {
    __shared__ unsigned short sB[3 * 66 * 72];
    __shared__ float sa_row[64];

    int t    = threadIdx.x;
    int wv   = t >> 6;
    int lane = t & 63;
    int n    = lane & 15;
    int quad = lane >> 4;
    int x0   = blockIdx.x * 64;
    int y    = blockIdx.y;
    int b    = blockIdx.z;
    int xn   = wv * 16;

    #pragma unroll
    for (int i = 0; i < 7; ++i) {
        int e = t + i * 256;
        if (e < 1584) {
            int r   = e / 528;
            int rem = e - r * 528;
            int xi  = rem >> 3;
            int cg  = rem & 7;
            int yy  = y + r - 1;
            int xx  = x0 - 1 + xi;
            uint4 v = make_uint4(0u, 0u, 0u, 0u);
            if (yy >= 0 && yy < H_ && xx >= 0 && xx < W_)
                v = *(const uint4*)(xdb + ((size_t)b * HW + (size_t)yy * W_ + xx) * 64 + cg * 8);
            *(uint4*)(sB + (r * 66 + xi) * 72 + cg * 8) = v;
        }
    }
    __syncthreads();

    f32x4 acc = (f32x4){0.f, 0.f, 0.f, 0.f};
    #pragma unroll
    for (int tap = 0; tap < 9; ++tap) {
        int dy = tap / 3, dx = tap % 3;
        #pragma unroll
        for (int kc = 0; kc < 2; ++kc) {
            short8 a  = *(const short8*)(Wsapk + (size_t)n * 576 + tap * 64 + kc * 32 + quad * 8);
            short8 bf = *(const short8*)(sB + (dy * 66 + xn + n + dx) * 72 + kc * 32 + quad * 8);
            acc = __builtin_amdgcn_mfma_f32_16x16x32_bf16(a, bf, acc, 0, 0, 0);
        }
    }
    if (quad == 0)
        sa_row[xn + n] = sigmoidf_(acc[0] + b_sa[0]);
    __syncthreads();

    // scale: thread -> (pixel t>>2, 16 channels (t&3)*16) from center row of sB
    int px_l = t >> 2;
    int cg   = (t & 3) * 16;
    float s_add = sa_row[px_l];
    uint4 v0 = *(const uint4*)(sB + (66 + px_l + 1) * 72 + cg);
    uint4 v1 = *(const uint4*)(sB + (66 + px_l + 1) * 72 + cg + 8);
    const unsigned short* sp0 = (const unsigned short*)&v0;
    const unsigned short* sp1 = (const unsigned short*)&v1;
    unsigned short pk[16];
    #pragma unroll
    for (int q = 0; q < 8; ++q) {
        pk[q]     = f2bf(bf2f(sp0[q]) * (ca[b * 64 + cg + q]     + s_add));
        pk[8 + q] = f2bf(bf2f(sp1[q]) * (ca[b * 64 + cg + 8 + q] + s_add));
    }
    unsigned short* xap = xa + ((size_t)b * HW + (size_t)y * W_ + x0 + px_l) * 64 + cg;
    *(uint4*)(xap)     = *(const uint4*)(pk);
    *(uint4*)(xap + 8) = *(const uint4*)(pk + 8);
}

// ---------------------------------------------------------------------------
// K6: r1 = leaky(1x1 conv 64->256) bf16 MFMA GEMM, per 2-BATCH slab.
// grid = 2*HW/64 = 1152.
// ---------------------------------------------------------------------------
__global__ __launch_bounds__(256) void k_r1_mfma(const unsigned short* __restrict__ xa_s,
                                                 const unsigned short* __restrict__ Apk1,
                                                 const float* __restrict__ b_r1,
                                                 unsigned short* __restrict__ tr) {
    int t    = threadIdx.x;
    int wv   = t >> 6;
    int lane = t & 63;
    int n    = lane & 15;
    int quad = lane >> 4;
    size_t p0 = (size_t)blockIdx.x * 64;

    f32x4 acc[4][4];
    #pragma unroll
    for (int i = 0; i < 4; ++i)
        #pragma unroll
        for (int j = 0; j < 4; ++j) acc[i][j] = (f32x4){0.f, 0.f, 0.f, 0.f};

    #pragma unroll
    for (int ks = 0; ks < 2; ++ks) {
        int k0 = ks * 32;
        short8 bfrag[4];
        #pragma unroll
        for (int jt = 0; jt < 4; ++jt)
            bfrag[jt] = *(const short8*)(xa_s + (p0 + jt * 16 + n) * 64 + k0 + quad * 8);
        #pragma unroll
        for (int mt = 0; mt < 4; ++mt) {
            short8 afrag = *(const short8*)(Apk1 + (wv * 64 + mt * 16 + n) * 64 + k0 + quad * 8);
            #pragma unroll
            for (int jt = 0; jt < 4; ++jt)
                acc[mt][jt] = __builtin_amdgcn_mfma_f32_16x16x32_bf16(afrag, bfrag[jt], acc[mt][jt], 0, 0, 0);
        }
    }
    #pragma unroll
    for (int mt = 0; mt < 4; ++mt) {
        int ocb = wv * 64 + mt * 16 + quad * 4;
        float b0 = b_r1[ocb], b1 = b_r1[ocb + 1], b2 = b_r1[ocb + 2], b3 = b_r1[ocb + 3];
        #pragma unroll
        for (int jt = 0; jt < 4; ++jt) {
            size_t p = p0 + jt * 16 + n;
            ushort4 pk;
            pk.x = f2bf(leakyf(acc[mt][jt][0] + b0));
            pk.y = f2bf(leakyf(acc[mt][jt][1] + b1));
            pk.z = f2bf(leakyf(acc[mt][jt][2] + b2));
            pk.w = f2bf(leakyf(acc[mt][jt][3] + b3));
            *(ushort4*)(tr + p * 256 + ocb) = pk;
        }
    }
}

// ---------------------------------------------------------------------------
// K7: r2 = 3x3 conv 256->64 bf16 MFMA, per 2-BATCH slab, half-row blocks.
// grid = (2, 192, 2).
// ---------------------------------------------------------------------------
#define R2P 40
__global__ __launch_bounds__(256) void k_r2_mfma(const unsigned short* __restrict__ tr_s,
                                                 const unsigned short* __restrict__ Apk2,
                                                 const float* __restrict__ b_r2,
                                                 float* __restrict__ out,
                                                 int b_base) {
    __shared__ unsigned short sB[3 * 98 * R2P];   // 23520 B

    int t     = threadIdx.x;
    int wv    = t >> 6;
    int lane  = t & 63;
    int n     = lane & 15;
    int quad  = lane >> 4;
    int xh    = blockIdx.x;
    int y     = blockIdx.y;
    int zb    = blockIdx.z;          // slab-local batch
    int x0    = xh * 96;
    int mbase = (wv & 1) * 32;
    int xbase = (wv >> 1) * 48;

    const unsigned short* tr = tr_s + (size_t)zb * HW * 256;

    f32x4 acc[2][3];
    #pragma unroll
    for (int i = 0; i < 2; ++i)
        #pragma unroll
        for (int j = 0; j < 3; ++j) acc[i][j] = (f32x4){0.f, 0.f, 0.f, 0.f};

    for (int c0 = 0; c0 < 256; c0 += 32) {
        __syncthreads();
        #pragma unroll
        for (int i = 0; i < 5; ++i) {
            int e = t + i * 256;
            if (e < 1176) {
                int r   = e / 392;
                int rem = e - r * 392;
                int xi  = rem >> 2;
                int cq  = rem & 3;
                int yy  = y + r - 1;
                int xx  = x0 - 1 + xi;
                uint4 v = make_uint4(0u, 0u, 0u, 0u);
                if (yy >= 0 && yy < H_ && xx >= 0 && xx < W_)
                    v = *(const uint4*)(tr + ((size_t)yy * W_ + xx) * 256 + c0 + cq * 8);
                *(uint4*)(sB + (r * 98 + xi) * R2P + cq * 8) = v;
            }
        }
        __syncthreads();
        #pragma unroll
        for (int tap = 0; tap < 9; ++tap) {
            int dy = tap / 3, dx = tap % 3;
            short8 a0 = *(const short8*)(Apk2 + (size_t)(mbase + n)      * 2304 + tap * 256 + c0 + quad * 8);
            short8 a1 = *(const short8*)(Apk2 + (size_t)(mbase + 16 + n) * 2304 + tap * 256 + c0 + quad * 8);
            #pragma unroll
            for (int j = 0; j < 3; ++j) {
                int xi = xbase + j * 16 + n + dx;
                short8 bf = *(const short8*)(sB + (dy * 98 + xi) * R2P + quad * 8);
                acc[0][j] = __builtin_amdgcn_mfma_f32_16x16x32_bf16(a0, bf, acc[0][j], 0, 0, 0);
                acc[1][j] = __builtin_amdgcn_mfma_f32_16x16x32_bf16(a1, bf, acc[1][j], 0, 0, 0);
            }
        }
    }
    #pragma unroll
    for (int mt = 0; mt < 2; ++mt) {
        int oc = mbase + mt * 16 + quad * 4;
        float b0 = b_r2[oc], b1 = b_r2[oc + 1], b2 = b_r2[oc + 2], b3 = b_r2[oc + 3];
        #pragma unroll
        for (int j = 0; j < 3; ++j) {
            int xx = x0 + xbase + j * 16 + n;
            float* op = out + ((size_t)(b_base + zb) * 64 + oc) * HW + y * W_ + xx;
            op[0]              = acc[mt][j][0] + b0;
            op[HW]             = acc[mt][j][1] + b1;
            op[2 * HW]         = acc[mt][j][2] + b2;
            op[3 * (size_t)HW] = acc[mt][j][3] + b3;
        }
    }
}

// ---------------------------------------------------------------------------
// K8: n1 = 1x1 conv 64->32 bf16 MFMA, out tn1 NHWC bf16. grid (576, 4).
// ---------------------------------------------------------------------------
__global__ __launch_bounds__(256) void k_n1_mfma(const unsigned short* __restrict__ xa,
                                                 const unsigned short* __restrict__ Wn1pk,
                                                 const float* __restrict__ b_n1,
                                                 unsigned short* __restrict__ tn1) {
    int t    = threadIdx.x;
    int wv   = t >> 6;
    int lane = t & 63;
    int n    = lane & 15;
    int quad = lane >> 4;
    int b    = blockIdx.y;
    int pix  = blockIdx.x * 64 + wv * 16 + n;

    f32x4 acc[2];
    acc[0] = (f32x4){0.f, 0.f, 0.f, 0.f};
    acc[1] = (f32x4){0.f, 0.f, 0.f, 0.f};

    #pragma unroll
    for (int ks = 0; ks < 2; ++ks) {
        short8 bf = *(const short8*)(xa + ((size_t)b * HW + pix) * 64 + ks * 32 + quad * 8);
        #pragma unroll
        for (int mt = 0; mt < 2; ++mt) {
            short8 a = *(const short8*)(Wn1pk + (size_t)(mt * 16 + n) * 64 + ks * 32 + quad * 8);
            acc[mt] = __builtin_amdgcn_mfma_f32_16x16x32_bf16(a, bf, acc[mt], 0, 0, 0);
        }
    }
    #pragma unroll
    for (int mt = 0; mt < 2; ++mt) {
        int oc = mt * 16 + quad * 4;
        ushort4 pk;
        pk.x = f2bf(acc[mt][0] + b_n1[oc]);
        pk.y = f2bf(acc[mt][1] + b_n1[oc + 1]);
        pk.z = f2bf(acc[mt][2] + b_n1[oc + 2]);
        pk.w = f2bf(acc[mt][3] + b_n1[oc + 3]);
        *(ushort4*)(tn1 + ((size_t)b * HW + pix) * 32 + oc) = pk;
    }
}

// ---------------------------------------------------------------------------
// K9: depthwise 3x3 on NHWC bf16, 32 channels. grid = (3, 192, 4).
// thread -> (pixel t>>2 within 64-px tile, 8 channels (t&3)*8)
// ---------------------------------------------------------------------------
__global__ __launch_bounds__(256) void k_dw3x3(const unsigned short* __restrict__ t1,
                                               const float* __restrict__ w,
                                               const float* __restrict__ bias,
                                               unsigned short* __restrict__ t2) {
    int t  = threadIdx.x;
    int px_l = t >> 2;
    int cg   = (t & 3) * 8;
    int x0 = blockIdx.x * 64;
    int y  = blockIdx.y;
    int b  = blockIdx.z;
    int xx = x0 + px_l;

    float acc[8];
    #pragma unroll
    for (int q = 0; q < 8; ++q) acc[q] = bias[cg + q];

    #pragma unroll
    for (int dy = -1; dy <= 1; ++dy) {
        int yy = y + dy;
        if (yy < 0 || yy >= H_) continue;
        #pragma unroll
        for (int dx = -1; dx <= 1; ++dx) {
            int xc = xx + dx;
            if (xc < 0 || xc >= W_) continue;
            short8 s = *(const short8*)(t1 + ((size_t)b * HW + (size_t)yy * W_ + xc) * 32 + cg);
            int tap = (dy + 1) * 3 + (dx + 1);
            #pragma unroll
            for (int q = 0; q < 8; ++q)
                acc[q] += w[(cg + q) * 9 + tap] * bf2f((unsigned short)s[q]);
        }
    }
    unsigned short pk[8];
    #pragma unroll
    for (int q = 0; q < 8; ++q) pk[q] = f2bf(acc[q]);
    *(uint4*)(t2 + ((size_t)b * HW + (size_t)y * W_ + xx) * 32 + cg) = *(const uint4*)pk;
}

// ---------------------------------------------------------------------------
// K10: out = x + xr(in d_out) + (w_n3 @ t2 + b_n3), MFMA K=32. grid (576,4).
// ---------------------------------------------------------------------------
__global__ __launch_bounds__(256) void k_final_mfma(const float* __restrict__ x,
                                                    const unsigned short* __restrict__ t2,
                                                    const unsigned short* __restrict__ Wn3pk,
                                                    const float* __restrict__ b_n3,
                                                    float* __restrict__ out) {
    int t    = threadIdx.x;
    int wv   = t >> 6;
    int lane = t & 63;
    int n    = lane & 15;
    int quad = lane >> 4;
    int b    = blockIdx.y;
    int pix  = blockIdx.x * 64 + wv * 16 + n;

    short8 bfrag = *(const short8*)(t2 + ((size_t)b * HW + pix) * 32 + quad * 8);

    f32x4 acc[4];
    #pragma unroll
    for (int ot = 0; ot < 4; ++ot) {
        short8 a = *(const short8*)(Wn3pk + (size_t)(ot * 16 + n) * 32 + quad * 8);
        acc[ot] = __builtin_amdgcn_mfma_f32_16x16x32_bf16(a, bfrag,
                    (f32x4){0.f, 0.f, 0.f, 0.f}, 0, 0, 0);
    }
    #pragma unroll
    for (int ot = 0; ot < 4; ++ot) {
        int oc = ot * 16 + quad * 4;
        #pragma unroll
        for (int reg = 0; reg < 4; ++reg) {
            size_t idx = ((size_t)b * 64 + oc + reg) * HW + pix;
            out[idx] = x[idx] + out[idx] + acc[ot][reg] + b_n3[oc + reg];
        }
    }
}

// ---------------------------------------------------------------------------
extern "C" void kernel_launch(void* const* d_in, const int* in_sizes, int n_in,
                              void* d_out, int out_size, void* d_ws, size_t ws_size,
                              hipStream_t stream) {
    const float* x     = (const float*)d_in[0];
    const float* w_off = (const float*)d_in[1];
    const float* b_off = (const float*)d_in[2];
    const float* w_dc  = (const float*)d_in[3];
    const float* b_dc  = (const float*)d_in[4];
    const float* w_ca1 = (const float*)d_in[5];
    const float* b_ca1 = (const float*)d_in[6];
    const float* w_ca2 = (const float*)d_in[7];
    const float* b_ca2 = (const float*)d_in[8];
    const float* w_sa  = (const float*)d_in[9];
    const float* b_sa  = (const float*)d_in[10];
    const float* w_r1  = (const float*)d_in[11];
    const float* b_r1  = (const float*)d_in[12];
    const float* w_r2  = (const float*)d_in[13];
    const float* b_r2  = (const float*)d_in[14];
    const float* w_n1  = (const float*)d_in[15];
    const float* b_n1  = (const float*)d_in[16];
    const float* w_n2  = (const float*)d_in[17];
    const float* b_n2  = (const float*)d_in[18];
    const float* w_n3  = (const float*)d_in[19];
    const float* b_n3  = (const float*)d_in[20];
    float* out = (float*)d_out;

    // ------------------------------------------------------------------
    // Workspace (float offsets). Total 20,990,720 f = 84.0 MB (< 92.2 proven).
    //  A [0,        4718592)  xd NHWC bf16 (deform->sa_scale);
    //                         then tn1 bf16 [0,2359296) + tn2 bf16 [2359296,4718592).
    //  B [4718592,  9437184)  xa NHWC bf16 (sa_scale -> r1 x2, n1).
    //  C [9437184, 11427840)  om bf16 (off -> deform).
    //  D [11427840,11553536)  ca_part, ca_o, prepacked weights.
    //  E [11553536,20990720)  x NHWC bf16 (first 4718592 f; dead after deform)
    //                         -> tr 2-batch bf16 (full 9437184 f).
    // ------------------------------------------------------------------
    float* ws = (float*)d_ws;
    unsigned short* xd_bhwc = (unsigned short*)ws;                    // A
    unsigned short* tn1     = (unsigned short*)ws;                    // A (late)
    unsigned short* tn2     = (unsigned short*)(ws + 2359296);        // A (late)
    unsigned short* xa_bhwc = (unsigned short*)(ws + 4718592);        // B
    unsigned short* om      = (unsigned short*)(ws + 9437184);        // C: 3981312 sh
    float* ca_part = ws + 11427840;                                   // 9216 f
    float* ca_o    = ws + 11437056;                                   // 256 f
    unsigned short* Apk1  = (unsigned short*)(ws + 11437312);         // 16384 sh
    unsigned short* Apk2  = Apk1 + 16384;                             // 147456 sh
    unsigned short* Wofpk = Apk2 + 147456;                            // 18432 sh
    unsigned short* Wdcb  = Wofpk + 18432;                            // 36864 sh
    unsigned short* Wsapk = Wdcb + 36864;                             // 9216 sh
    unsigned short* Wn1pk = Wsapk + 9216;                             // 2048 sh
    unsigned short* Wn3pk = Wn1pk + 2048;                             // 2048 sh
    unsigned short* x_bhwc = (unsigned short*)(ws + 11553536);        // E (early)
    unsigned short* trh    = (unsigned short*)(ws + 11553536);        // E (after deform)

    k_x_t        <<<dim3(HW / 64, 4), 256, 0, stream>>>(x, x_bhwc);
    k_prepack    <<<908, 256, 0, stream>>>(w_r1, w_r2, w_off, w_dc, w_sa, w_n1, w_n3,
                                           Apk1, Apk2, Wofpk, Wdcb, Wsapk, Wn1pk, Wn3pk);
    k_off_mfma   <<<dim3(3, 192, 4), 256, 0, stream>>>(x_bhwc, Wofpk, b_off, om);
    k_deform_mfma<<<dim3(576, 4), 256, 0, stream>>>(x_bhwc, om, Wdcb, b_dc, xd_bhwc);
    k_camean     <<<dim3(36, 4), 256, 0, stream>>>(xd_bhwc, ca_part);
    k_ca_mlp     <<<1, 256, 0, stream>>>(ca_part, w_ca1, b_ca1, w_ca2, b_ca2, ca_o);
    k_sa_scale   <<<dim3(3, 192, 4), 256, 0, stream>>>(xd_bhwc, Wsapk, b_sa, ca_o, xa_bhwc);

    // r-branch: two 2-batch slabs through tr (stream-serialized)
    for (int s = 0; s < 2; ++s) {
        k_r1_mfma<<<(2 * HW) / 64, 256, 0, stream>>>(xa_bhwc + (size_t)s * 2 * HW * 64,
                                                     Apk1, b_r1, trh);
        k_r2_mfma<<<dim3(2, 192, 2), 256, 0, stream>>>(trh, Apk2, b_r2, out, s * 2);
    }

    // n-branch (NHWC bf16 throughout)
    k_n1_mfma   <<<dim3(576, 4), 256, 0, stream>>>(xa_bhwc, Wn1pk, b_n1, tn1);
    k_dw3x3     <<<dim3(3, 192, 4), 256, 0, stream>>>(tn1, w_n2, b_n2, tn2);
    k_final_mfma<<<dim3(576, 4), 256, 0, stream>>>(x, tn2, Wn3pk, b_n3, out);
}

// Round 8
// 509.562 us; speedup vs baseline: 12.0270x; 1.1710x over previous
//
#include <hip/hip_runtime.h>
#include <hip/hip_bf16.h>
#include <math.h>

#define B_  4
#define C_  64
#define H_  192
#define W_  192
#define HW  36864           // H_*W_
#define CHW 2359296         // C_*HW

typedef __attribute__((ext_vector_type(8))) short short8;
typedef __attribute__((ext_vector_type(4))) float f32x4;

__device__ __forceinline__ float leakyf(float v) { return v >= 0.f ? v : 0.1f * v; }
__device__ __forceinline__ float sigmoidf_(float v) { return 1.f / (1.f + __expf(-v)); }
__device__ __forceinline__ unsigned short f2bf(float f) {
    union { float f; unsigned u; } v; v.f = f;
    unsigned r = v.u + 0x7fff + ((v.u >> 16) & 1);   // round-to-nearest-even
    return (unsigned short)(r >> 16);
}
__device__ __forceinline__ float bf2f(unsigned short s) {
    union { unsigned u; float f; } cv; cv.u = ((unsigned)s) << 16; return cv.f;
}

// ---------------------------------------------------------------------------
// K-1: x (NCHW fp32) -> x_bhwc (NHWC bf16) via LDS transpose
// ---------------------------------------------------------------------------
__global__ __launch_bounds__(256) void k_x_t(const float* __restrict__ x,
                                             unsigned short* __restrict__ xb16) {
    __shared__ unsigned short sT[64 * 72];
    int t  = threadIdx.x;
    int p0 = blockIdx.x * 64;
    int b  = blockIdx.y;
    const float* xb = x + (size_t)b * CHW + p0;
    #pragma unroll
    for (int i = 0; i < 16; ++i) {
        int e = t + i * 256;
        int c = e >> 6, pp = e & 63;
        sT[pp * 72 + c] = f2bf(xb[(size_t)c * HW + pp]);
    }
    __syncthreads();
    unsigned short* xap = xb16 + ((size_t)b * HW + p0) * 64;
    #pragma unroll
    for (int i = 0; i < 2; ++i) {
        int e = t + i * 256;
        int pp = e >> 3, cq = e & 7;
        *(uint4*)(xap + pp * 64 + cq * 8) = *(const uint4*)(sT + pp * 72 + cq * 8);
    }
}

// ---------------------------------------------------------------------------
// K0: prepack all MFMA weights to bf16. 908 blocks x 256 covers 232448 items.
// ---------------------------------------------------------------------------
__global__ void k_prepack(const float* __restrict__ w_r1, const float* __restrict__ w_r2,
                          const float* __restrict__ w_off, const float* __restrict__ w_dc,
                          const float* __restrict__ w_sa, const float* __restrict__ w_n1,
                          const float* __restrict__ w_n3,
                          unsigned short* __restrict__ Apk1, unsigned short* __restrict__ Apk2,
                          unsigned short* __restrict__ Wofpk, unsigned short* __restrict__ Wdcb,
                          unsigned short* __restrict__ Wsapk, unsigned short* __restrict__ Wn1pk,
                          unsigned short* __restrict__ Wn3pk) {
    int t = blockIdx.x * 256 + threadIdx.x;
    if (t < 16384) { Apk1[t] = f2bf(w_r1[t]); return; }
    int e = t - 16384;
    if (e < 147456) {
        int oc = e / 2304, r = e % 2304, tap = r / 256, c = r & 255;
        Apk2[e] = f2bf(w_r2[(oc * 256 + c) * 9 + tap]);
        return;
    }
    e -= 147456;
    if (e < 18432) {
        int m = e / 576, r = e % 576, tap = r / 64, c = r & 63;
        Wofpk[e] = (m < 27) ? f2bf(w_off[m * 576 + c * 9 + tap]) : (unsigned short)0;
        return;
    }
    e -= 18432;
    if (e < 36864) {
        int c = e & 63, r = e >> 6, k = r / 64, o = r & 63;
        Wdcb[e] = f2bf(w_dc[(o * 64 + c) * 9 + k]);
        return;
    }
    e -= 36864;
    if (e < 9216) {
        int m = e / 576, r = e % 576, tap = r / 64, c = r & 63;
        Wsapk[e] = (m == 0) ? f2bf(w_sa[c * 9 + tap]) : (unsigned short)0;
        return;
    }
    e -= 9216;
    if (e < 2048) { Wn1pk[e] = f2bf(w_n1[e]); return; }
    e -= 2048;
    if (e < 2048) Wn3pk[e] = f2bf(w_n3[e]);
}

// ---------------------------------------------------------------------------
// K1: offset/mask conv bf16 MFMA; output om in bf16. grid = (3, 192, 4).
// ---------------------------------------------------------------------------
__global__ __launch_bounds__(256) void k_off_mfma(const unsigned short* __restrict__ xb16,
                                                  const unsigned short* __restrict__ Wofpk,
                                                  const float* __restrict__ b_off,
                                                  unsigned short* __restrict__ om) {
    __shared__ unsigned short sB[3 * 66 * 72];   // 28512 B

    int t    = threadIdx.x;
    int wv   = t >> 6;
    int lane = t & 63;
    int n    = lane & 15;
    int quad = lane >> 4;
    int x0   = blockIdx.x * 64;
    int y    = blockIdx.y;
    int b    = blockIdx.z;
    int xn   = wv * 16;

    #pragma unroll
    for (int i = 0; i < 7; ++i) {
        int e = t + i * 256;
        if (e < 1584) {
            int r   = e / 528;
            int rem = e - r * 528;
            int xi  = rem >> 3;
            int cg  = rem & 7;
            int yy  = y + r - 1;
            int xx  = x0 - 1 + xi;
            uint4 v = make_uint4(0u, 0u, 0u, 0u);
            if (yy >= 0 && yy < H_ && xx >= 0 && xx < W_)
                v = *(const uint4*)(xb16 + ((size_t)b * HW + (size_t)yy * W_ + xx) * 64 + cg * 8);
            *(uint4*)(sB + (r * 66 + xi) * 72 + cg * 8) = v;
        }
    }
    __syncthreads();

    f32x4 acc[2];
    acc[0] = (f32x4){0.f, 0.f, 0.f, 0.f};
    acc[1] = (f32x4){0.f, 0.f, 0.f, 0.f};

    #pragma unroll
    for (int tap = 0; tap < 9; ++tap) {
        int dy = tap / 3, dx = tap % 3;
        #pragma unroll
        for (int kc = 0; kc < 2; ++kc) {
            short8 a0 = *(const short8*)(Wofpk + (size_t)n        * 576 + tap * 64 + kc * 32 + quad * 8);
            short8 a1 = *(const short8*)(Wofpk + (size_t)(16 + n) * 576 + tap * 64 + kc * 32 + quad * 8);
            short8 bf = *(const short8*)(sB + (dy * 66 + xn + n + dx) * 72 + kc * 32 + quad * 8);
            acc[0] = __builtin_amdgcn_mfma_f32_16x16x32_bf16(a0, bf, acc[0], 0, 0, 0);
            acc[1] = __builtin_amdgcn_mfma_f32_16x16x32_bf16(a1, bf, acc[1], 0, 0, 0);
        }
    }

    int xx = x0 + xn + n;
    #pragma unroll
    for (int mt = 0; mt < 2; ++mt) {
        #pragma unroll
        for (int reg = 0; reg < 4; ++reg) {
            int oc = mt * 16 + quad * 4 + reg;
            if (oc < 27) {
                float v = leakyf(acc[mt][reg] + b_off[oc]);
                if (oc >= 18) v = sigmoidf_(v);
                om[((size_t)b * 27 + oc) * HW + (size_t)y * W_ + xx] = f2bf(v);
            }
        }
    }
}

// ---------------------------------------------------------------------------
// K2: deformable conv, LDS-staged MFMA (R6 structure). Block = 64 pixels.
// Phase 0: precompute bilinear params for all 9 taps (LDS sidx/swgt).
// Per k: gather+blend -> val[64p][64c] bf16 LDS -> MFMA 64o x 64c x 64p.
// Output xd NHWC bf16. grid = (576, 4).
// ---------------------------------------------------------------------------
__global__ __launch_bounds__(256) void k_deform_mfma(const unsigned short* __restrict__ xb16,
                                                     const unsigned short* __restrict__ om,
                                                     const unsigned short* __restrict__ Wdcb,
                                                     const float* __restrict__ bias,
                                                     unsigned short* __restrict__ xdb) {
    __shared__ unsigned short val[64 * 72];   // 9216 B
    __shared__ int   sidx[9][4][64];          // 9216 B
    __shared__ float swgt[9][4][64];          // 9216 B

    int t    = threadIdx.x;
    int wv   = t >> 6;
    int lane = t & 63;
    int n    = lane & 15;
    int quad = lane >> 4;
    int b    = blockIdx.y;
    int px0  = blockIdx.x * 64;
    int pp   = t >> 2;            // gather pixel 0..63
    int c0   = (t & 3) * 16;      // gather channel group

    f32x4 acc[4];
    #pragma unroll
    for (int i = 0; i < 4; ++i) acc[i] = (f32x4){0.f, 0.f, 0.f, 0.f};

    const unsigned short* xbh = xb16 + (size_t)b * HW * 64;
    const unsigned short* omb = om + (size_t)b * 27 * HW;

    // Phase 0: bilinear params for all (k, pixel) pairs: 576 entries
    #pragma unroll
    for (int i = 0; i < 3; ++i) {
        int e = t + i * 256;
        if (e < 576) {
            int k    = e >> 6;
            int px_l = e & 63;
            int pix  = px0 + px_l;
            int py_i = pix / W_;
            int px_i = pix - py_i * W_;
            float offy = bf2f(omb[(size_t)(2 * k)     * HW + pix]);
            float offx = bf2f(omb[(size_t)(2 * k + 1) * HW + pix]);
            float m    = bf2f(omb[(size_t)(18 + k)    * HW + pix]);
            float py = (float)py_i + (float)(k / 3 - 1) + offy;
            float px = (float)px_i + (float)(k % 3 - 1) + offx;
            float y0f = floorf(py), x0f = floorf(px);
            float wy = py - y0f, wx = px - x0f;
            int y0 = (int)y0f, x0 = (int)x0f;
            #pragma unroll
            for (int j = 0; j < 4; ++j) {
                int yy = y0 + (j >> 1);
                int xx = x0 + (j & 1);
                bool v = (yy >= 0) && (yy < H_) && (xx >= 0) && (xx < W_);
                int yc  = min(max(yy, 0), H_ - 1);
                int xcl = min(max(xx, 0), W_ - 1);
                sidx[k][j][px_l] = yc * W_ + xcl;
                float wj = ((j >> 1) ? wy : 1.f - wy) * ((j & 1) ? wx : 1.f - wx);
                swgt[k][j][px_l] = v ? wj * m : 0.f;
            }
        }
    }
    __syncthreads();

    for (int k = 0; k < 9; ++k) {
        // gather + bilinear blend (fp32), convert to bf16 into val
        {
            float vf[16];
            #pragma unroll
            for (int q = 0; q < 16; ++q) vf[q] = 0.f;
            #pragma unroll
            for (int j = 0; j < 4; ++j) {
                float w = swgt[k][j][pp];
                const unsigned short* src = xbh + (size_t)sidx[k][j][pp] * 64 + c0;
                short8 s0 = *(const short8*)(src);
                short8 s1 = *(const short8*)(src + 8);
                #pragma unroll
                for (int q = 0; q < 8; ++q) {
                    vf[q]     += w * bf2f((unsigned short)s0[q]);
                    vf[8 + q] += w * bf2f((unsigned short)s1[q]);
                }
            }
            unsigned short pk[16];
            #pragma unroll
            for (int q = 0; q < 16; ++q) pk[q] = f2bf(vf[q]);
            *(uint4*)(val + pp * 72 + c0)     = *(const uint4*)(pk);
            *(uint4*)(val + pp * 72 + c0 + 8) = *(const uint4*)(pk + 8);
        }
        __syncthreads();
        // MFMA: o-tile = wv (16 oc), all 4 p-tiles, K=64
        #pragma unroll
        for (int ks = 0; ks < 2; ++ks) {
            short8 a = *(const short8*)(Wdcb + ((size_t)(k * 64 + wv * 16 + n)) * 64 + ks * 32 + quad * 8);
            #pragma unroll
            for (int pt = 0; pt < 4; ++pt) {
                short8 bf = *(const short8*)(val + (pt * 16 + n) * 72 + ks * 32 + quad * 8);
                acc[pt] = __builtin_amdgcn_mfma_f32_16x16x32_bf16(a, bf, acc[pt], 0, 0, 0);
            }
        }
        __syncthreads();   // val reused next iteration
    }
    // epilogue: D row = oc (quad*4+reg within wave's 16), col = pixel (n)
    int ocb = wv * 16 + quad * 4;
    float b0 = bias[ocb], b1 = bias[ocb + 1], b2 = bias[ocb + 2], b3 = bias[ocb + 3];
    #pragma unroll
    for (int pt = 0; pt < 4; ++pt) {
        int pix = px0 + pt * 16 + n;
        ushort4 pk;
        pk.x = f2bf(acc[pt][0] + b0);
        pk.y = f2bf(acc[pt][1] + b1);
        pk.z = f2bf(acc[pt][2] + b2);
        pk.w = f2bf(acc[pt][3] + b3);
        *(ushort4*)(xdb + ((size_t)b * HW + pix) * 64 + ocb) = pk;
    }
}

// ---------------------------------------------------------------------------
// K3a: per-(b,c) partial spatial sums of xd (NHWC bf16). grid = (36, 4).
// ---------------------------------------------------------------------------
__global__ __launch_bounds__(256) void k_camean(const unsigned short* __restrict__ xdb,
                                                float* __restrict__ ca_part) {
    int t = threadIdx.x;
    int chunk = blockIdx.x;
    int b = blockIdx.y;
    int c = t & 63, sub = t >> 6;
    const unsigned short* base = xdb + ((size_t)b * HW + chunk * 1024 + sub * 256) * 64 + c;
    float s = 0.f;
    for (int i = 0; i < 256; ++i) s += bf2f(base[(size_t)i * 64]);
    __shared__ float sm[256];
    sm[t] = s;
    __syncthreads();
    if (t < 64)
        ca_part[((size_t)b * 36 + chunk) * 64 + t] = sm[t] + sm[64 + t] + sm[128 + t] + sm[192 + t];
}

// ---------------------------------------------------------------------------
// K3b: reduce partials + tiny MLP 64->8(relu)->64(sigmoid), one block.
// ---------------------------------------------------------------------------
__global__ __launch_bounds__(256) void k_ca_mlp(const float* __restrict__ ca_part,
                                                const float* __restrict__ w1,
                                                const float* __restrict__ b1,
                                                const float* __restrict__ w2,
                                                const float* __restrict__ b2,
                                                float* __restrict__ ca_out) {
    __shared__ float cain[256];
    __shared__ float h[32];
    int t = threadIdx.x;
    {
        int b = t >> 6, c = t & 63;
        float s = 0.f;
        #pragma unroll
        for (int j = 0; j < 36; ++j) s += ca_part[((size_t)b * 36 + j) * 64 + c];
        cain[t] = s * (1.f / (float)HW);
    }
    __syncthreads();
    if (t < 32) {
        int b = t >> 3, j = t & 7;
        float a = b1[j];
        for (int c = 0; c < 64; ++c) a += w1[j * 64 + c] * cain[b * 64 + c];
        h[t] = a > 0.f ? a : 0.f;
    }
    __syncthreads();
    int b = t >> 6, c = t & 63;
    float a = b2[c];
    #pragma unroll
    for (int j = 0; j < 8; ++j) a += w2[c * 8 + j] * h[b * 8 + j];
    ca_out[t] = sigmoidf_(a);
}

// ---------------------------------------------------------------------------
// K4: FUSED spatial attention + scale. MFMA 3x3 conv 64->1 + sigmoid, then
// xa = xd * (ca + sa) from the already-staged center row in sB.
// grid = (3, 192, 4).
// ---------------------------------------------------------------------------
__global__ __launch_bounds__(256) void k_sa_scale(const unsigned short* __restrict__ xdb,
                                                  const unsigned short* __restrict__ Wsapk,
                                                  const float* __restrict__ b_sa,
                                                  const float* __restrict__ ca,
                                                  unsigned short* __restrict__ xa) {
    __shared__ unsigned short sB[3 * 66 * 72];
    __shared__ float sa_row[64];

    int t    = threadIdx.x;
    int wv   = t >> 6;
    int lane = t & 63;
    int n    = lane & 15;
    int quad = lane >> 4;
    int x0   = blockIdx.x * 64;
    int y    = blockIdx.y;
    int b    = blockIdx.z;
    int xn   = wv * 16;

    #pragma unroll
    for (int i = 0; i < 7; ++i) {
        int e = t + i * 256;
        if (e < 1584) {
            int r   = e / 528;
            int rem = e - r * 528;
            int xi  = rem >> 3;
            int cg  = rem & 7;
            int yy  = y + r - 1;
            int xx  = x0 - 1 + xi;
            uint4 v = make_uint4(0u, 0u, 0u, 0u);
            if (yy >= 0 && yy < H_ && xx >= 0 && xx < W_)
                v = *(const uint4*)(xdb + ((size_t)b * HW + (size_t)yy * W_ + xx) * 64 + cg * 8);
            *(uint4*)(sB + (r * 66 + xi) * 72 + cg * 8) = v;
        }
    }
    __syncthreads();

    f32x4 acc = (f32x4){0.f, 0.f, 0.f, 0.f};
    #pragma unroll
    for (int tap = 0; tap < 9; ++tap) {
        int dy = tap / 3, dx = tap % 3;
        #pragma unroll
        for (int kc = 0; kc < 2; ++kc) {
            short8 a  = *(const short8*)(Wsapk + (size_t)n * 576 + tap * 64 + kc * 32 + quad * 8);
            short8 bf = *(const short8*)(sB + (dy * 66 + xn + n + dx) * 72 + kc * 32 + quad * 8);
            acc = __builtin_amdgcn_mfma_f32_16x16x32_bf16(a, bf, acc, 0, 0, 0);
        }
    }
    if (quad == 0)
        sa_row[xn + n] = sigmoidf_(acc[0] + b_sa[0]);
    __syncthreads();

    // scale: thread -> (pixel t>>2, 16 channels (t&3)*16) from center row of sB
    int px_l = t >> 2;
    int cg   = (t & 3) * 16;
    float s_add = sa_row[px_l];
    uint4 v0 = *(const uint4*)(sB + (66 + px_l + 1) * 72 + cg);
    uint4 v1 = *(const uint4*)(sB + (66 + px_l + 1) * 72 + cg + 8);
    const unsigned short* sp0 = (const unsigned short*)&v0;
    const unsigned short* sp1 = (const unsigned short*)&v1;
    unsigned short pk[16];
    #pragma unroll
    for (int q = 0; q < 8; ++q) {
        pk[q]     = f2bf(bf2f(sp0[q]) * (ca[b * 64 + cg + q]     + s_add));
        pk[8 + q] = f2bf(bf2f(sp1[q]) * (ca[b * 64 + cg + 8 + q] + s_add));
    }
    unsigned short* xap = xa + ((size_t)b * HW + (size_t)y * W_ + x0 + px_l) * 64 + cg;
    *(uint4*)(xap)     = *(const uint4*)(pk);
    *(uint4*)(xap + 8) = *(const uint4*)(pk + 8);
}

// ---------------------------------------------------------------------------
// K6: r1 = leaky(1x1 conv 64->256) bf16 MFMA GEMM, per 2-BATCH slab.
// grid = 2*HW/64 = 1152.
// ---------------------------------------------------------------------------
__global__ __launch_bounds__(256) void k_r1_mfma(const unsigned short* __restrict__ xa_s,
                                                 const unsigned short* __restrict__ Apk1,
                                                 const float* __restrict__ b_r1,
                                                 unsigned short* __restrict__ tr) {
    int t    = threadIdx.x;
    int wv   = t >> 6;
    int lane = t & 63;
    int n    = lane & 15;
    int quad = lane >> 4;
    size_t p0 = (size_t)blockIdx.x * 64;

    f32x4 acc[4][4];
    #pragma unroll
    for (int i = 0; i < 4; ++i)
        #pragma unroll
        for (int j = 0; j < 4; ++j) acc[i][j] = (f32x4){0.f, 0.f, 0.f, 0.f};

    #pragma unroll
    for (int ks = 0; ks < 2; ++ks) {
        int k0 = ks * 32;
        short8 bfrag[4];
        #pragma unroll
        for (int jt = 0; jt < 4; ++jt)
            bfrag[jt] = *(const short8*)(xa_s + (p0 + jt * 16 + n) * 64 + k0 + quad * 8);
        #pragma unroll
        for (int mt = 0; mt < 4; ++mt) {
            short8 afrag = *(const short8*)(Apk1 + (wv * 64 + mt * 16 + n) * 64 + k0 + quad * 8);
            #pragma unroll
            for (int jt = 0; jt < 4; ++jt)
                acc[mt][jt] = __builtin_amdgcn_mfma_f32_16x16x32_bf16(afrag, bfrag[jt], acc[mt][jt], 0, 0, 0);
        }
    }
    #pragma unroll
    for (int mt = 0; mt < 4; ++mt) {
        int ocb = wv * 64 + mt * 16 + quad * 4;
        float b0 = b_r1[ocb], b1 = b_r1[ocb + 1], b2 = b_r1[ocb + 2], b3 = b_r1[ocb + 3];
        #pragma unroll
        for (int jt = 0; jt < 4; ++jt) {
            size_t p = p0 + jt * 16 + n;
            ushort4 pk;
            pk.x = f2bf(leakyf(acc[mt][jt][0] + b0));
            pk.y = f2bf(leakyf(acc[mt][jt][1] + b1));
            pk.z = f2bf(leakyf(acc[mt][jt][2] + b2));
            pk.w = f2bf(leakyf(acc[mt][jt][3] + b3));
            *(ushort4*)(tr + p * 256 + ocb) = pk;
        }
    }
}

// ---------------------------------------------------------------------------
// K7: r2 = 3x3 conv 256->64 bf16 MFMA, per 2-BATCH slab, half-row blocks.
// grid = (2, 192, 2).
// ---------------------------------------------------------------------------
#define R2P 40
__global__ __launch_bounds__(256) void k_r2_mfma(const unsigned short* __restrict__ tr_s,
                                                 const unsigned short* __restrict__ Apk2,
                                                 const float* __restrict__ b_r2,
                                                 float* __restrict__ out,
                                                 int b_base) {
    __shared__ unsigned short sB[3 * 98 * R2P];   // 23520 B

    int t     = threadIdx.x;
    int wv    = t >> 6;
    int lane  = t & 63;
    int n     = lane & 15;
    int quad  = lane >> 4;
    int xh    = blockIdx.x;
    int y     = blockIdx.y;
    int zb    = blockIdx.z;          // slab-local batch
    int x0    = xh * 96;
    int mbase = (wv & 1) * 32;
    int xbase = (wv >> 1) * 48;

    const unsigned short* tr = tr_s + (size_t)zb * HW * 256;

    f32x4 acc[2][3];
    #pragma unroll
    for (int i = 0; i < 2; ++i)
        #pragma unroll
        for (int j = 0; j < 3; ++j) acc[i][j] = (f32x4){0.f, 0.f, 0.f, 0.f};

    for (int c0 = 0; c0 < 256; c0 += 32) {
        __syncthreads();
        #pragma unroll
        for (int i = 0; i < 5; ++i) {
            int e = t + i * 256;
            if (e < 1176) {
                int r   = e / 392;
                int rem = e - r * 392;
                int xi  = rem >> 2;
                int cq  = rem & 3;
                int yy  = y + r - 1;
                int xx  = x0 - 1 + xi;
                uint4 v = make_uint4(0u, 0u, 0u, 0u);
                if (yy >= 0 && yy < H_ && xx >= 0 && xx < W_)
                    v = *(const uint4*)(tr + ((size_t)yy * W_ + xx) * 256 + c0 + cq * 8);
                *(uint4*)(sB + (r * 98 + xi) * R2P + cq * 8) = v;
            }
        }
        __syncthreads();
        #pragma unroll
        for (int tap = 0; tap < 9; ++tap) {
            int dy = tap / 3, dx = tap % 3;
            short8 a0 = *(const short8*)(Apk2 + (size_t)(mbase + n)      * 2304 + tap * 256 + c0 + quad * 8);
            short8 a1 = *(const short8*)(Apk2 + (size_t)(mbase + 16 + n) * 2304 + tap * 256 + c0 + quad * 8);
            #pragma unroll
            for (int j = 0; j < 3; ++j) {
                int xi = xbase + j * 16 + n + dx;
                short8 bf = *(const short8*)(sB + (dy * 98 + xi) * R2P + quad * 8);
                acc[0][j] = __builtin_amdgcn_mfma_f32_16x16x32_bf16(a0, bf, acc[0][j], 0, 0, 0);
                acc[1][j] = __builtin_amdgcn_mfma_f32_16x16x32_bf16(a1, bf, acc[1][j], 0, 0, 0);
            }
        }
    }
    #pragma unroll
    for (int mt = 0; mt < 2; ++mt) {
        int oc = mbase + mt * 16 + quad * 4;
        float b0 = b_r2[oc], b1 = b_r2[oc + 1], b2 = b_r2[oc + 2], b3 = b_r2[oc + 3];
        #pragma unroll
        for (int j = 0; j < 3; ++j) {
            int xx = x0 + xbase + j * 16 + n;
            float* op = out + ((size_t)(b_base + zb) * 64 + oc) * HW + y * W_ + xx;
            op[0]              = acc[mt][j][0] + b0;
            op[HW]             = acc[mt][j][1] + b1;
            op[2 * HW]         = acc[mt][j][2] + b2;
            op[3 * (size_t)HW] = acc[mt][j][3] + b3;
        }
    }
}

// ---------------------------------------------------------------------------
// K8: n1 = 1x1 conv 64->32 bf16 MFMA, out tn1 NHWC bf16. grid (576, 4).
// ---------------------------------------------------------------------------
__global__ __launch_bounds__(256) void k_n1_mfma(const unsigned short* __restrict__ xa,
                                                 const unsigned short* __restrict__ Wn1pk,
                                                 const float* __restrict__ b_n1,
                                                 unsigned short* __restrict__ tn1) {
    int t    = threadIdx.x;
    int wv   = t >> 6;
    int lane = t & 63;
    int n    = lane & 15;
    int quad = lane >> 4;
    int b    = blockIdx.y;
    int pix  = blockIdx.x * 64 + wv * 16 + n;

    f32x4 acc[2];
    acc[0] = (f32x4){0.f, 0.f, 0.f, 0.f};
    acc[1] = (f32x4){0.f, 0.f, 0.f, 0.f};

    #pragma unroll
    for (int ks = 0; ks < 2; ++ks) {
        short8 bf = *(const short8*)(xa + ((size_t)b * HW + pix) * 64 + ks * 32 + quad * 8);
        #pragma unroll
        for (int mt = 0; mt < 2; ++mt) {
            short8 a = *(const short8*)(Wn1pk + (size_t)(mt * 16 + n) * 64 + ks * 32 + quad * 8);
            acc[mt] = __builtin_amdgcn_mfma_f32_16x16x32_bf16(a, bf, acc[mt], 0, 0, 0);
        }
    }
    #pragma unroll
    for (int mt = 0; mt < 2; ++mt) {
        int oc = mt * 16 + quad * 4;
        ushort4 pk;
        pk.x = f2bf(acc[mt][0] + b_n1[oc]);
        pk.y = f2bf(acc[mt][1] + b_n1[oc + 1]);
        pk.z = f2bf(acc[mt][2] + b_n1[oc + 2]);
        pk.w = f2bf(acc[mt][3] + b_n1[oc + 3]);
        *(ushort4*)(tn1 + ((size_t)b * HW + pix) * 32 + oc) = pk;
    }
}

// ---------------------------------------------------------------------------
// K9: depthwise 3x3 on NHWC bf16, 32 channels. grid = (3, 192, 4).
// ---------------------------------------------------------------------------
__global__ __launch_bounds__(256) void k_dw3x3(const unsigned short* __restrict__ t1,
                                               const float* __restrict__ w,
                                               const float* __restrict__ bias,
                                               unsigned short* __restrict__ t2) {
    int t  = threadIdx.x;
    int px_l = t >> 2;
    int cg   = (t & 3) * 8;
    int x0 = blockIdx.x * 64;
    int y  = blockIdx.y;
    int b  = blockIdx.z;
    int xx = x0 + px_l;

    float acc[8];
    #pragma unroll
    for (int q = 0; q < 8; ++q) acc[q] = bias[cg + q];

    #pragma unroll
    for (int dy = -1; dy <= 1; ++dy) {
        int yy = y + dy;
        if (yy < 0 || yy >= H_) continue;
        #pragma unroll
        for (int dx = -1; dx <= 1; ++dx) {
            int xc = xx + dx;
            if (xc < 0 || xc >= W_) continue;
            short8 s = *(const short8*)(t1 + ((size_t)b * HW + (size_t)yy * W_ + xc) * 32 + cg);
            int tap = (dy + 1) * 3 + (dx + 1);
            #pragma unroll
            for (int q = 0; q < 8; ++q)
                acc[q] += w[(cg + q) * 9 + tap] * bf2f((unsigned short)s[q]);
        }
    }
    unsigned short pk[8];
    #pragma unroll
    for (int q = 0; q < 8; ++q) pk[q] = f2bf(acc[q]);
    *(uint4*)(t2 + ((size_t)b * HW + (size_t)y * W_ + xx) * 32 + cg) = *(const uint4*)pk;
}

// ---------------------------------------------------------------------------
// K10: out = x + xr(in d_out) + (w_n3 @ t2 + b_n3), MFMA K=32. grid (576,4).
// ---------------------------------------------------------------------------
__global__ __launch_bounds__(256) void k_final_mfma(const float* __restrict__ x,
                                                    const unsigned short* __restrict__ t2,
                                                    const unsigned short* __restrict__ Wn3pk,
                                                    const float* __restrict__ b_n3,
                                                    float* __restrict__ out) {
    int t    = threadIdx.x;
    int wv   = t >> 6;
    int lane = t & 63;
    int n    = lane & 15;
    int quad = lane >> 4;
    int b    = blockIdx.y;
    int pix  = blockIdx.x * 64 + wv * 16 + n;

    short8 bfrag = *(const short8*)(t2 + ((size_t)b * HW + pix) * 32 + quad * 8);

    f32x4 acc[4];
    #pragma unroll
    for (int ot = 0; ot < 4; ++ot) {
        short8 a = *(const short8*)(Wn3pk + (size_t)(ot * 16 + n) * 32 + quad * 8);
        acc[ot] = __builtin_amdgcn_mfma_f32_16x16x32_bf16(a, bfrag,
                    (f32x4){0.f, 0.f, 0.f, 0.f}, 0, 0, 0);
    }
    #pragma unroll
    for (int ot = 0; ot < 4; ++ot) {
        int oc = ot * 16 + quad * 4;
        #pragma unroll
        for (int reg = 0; reg < 4; ++reg) {
            size_t idx = ((size_t)b * 64 + oc + reg) * HW + pix;
            out[idx] = x[idx] + out[idx] + acc[ot][reg] + b_n3[oc + reg];
        }
    }
}

// ---------------------------------------------------------------------------
extern "C" void kernel_launch(void* const* d_in, const int* in_sizes, int n_in,
                              void* d_out, int out_size, void* d_ws, size_t ws_size,
                              hipStream_t stream) {
    const float* x     = (const float*)d_in[0];
    const float* w_off = (const float*)d_in[1];
    const float* b_off = (const float*)d_in[2];
    const float* w_dc  = (const float*)d_in[3];
    const float* b_dc  = (const float*)d_in[4];
    const float* w_ca1 = (const float*)d_in[5];
    const float* b_ca1 = (const float*)d_in[6];
    const float* w_ca2 = (const float*)d_in[7];
    const float* b_ca2 = (const float*)d_in[8];
    const float* w_sa  = (const float*)d_in[9];
    const float* b_sa  = (const float*)d_in[10];
    const float* w_r1  = (const float*)d_in[11];
    const float* b_r1  = (const float*)d_in[12];
    const float* w_r2  = (const float*)d_in[13];
    const float* b_r2  = (const float*)d_in[14];
    const float* w_n1  = (const float*)d_in[15];
    const float* b_n1  = (const float*)d_in[16];
    const float* w_n2  = (const float*)d_in[17];
    const float* b_n2  = (const float*)d_in[18];
    const float* w_n3  = (const float*)d_in[19];
    const float* b_n3  = (const float*)d_in[20];
    float* out = (float*)d_out;

    // ------------------------------------------------------------------
    // Workspace (float offsets). Total 20,990,720 f = 84.0 MB (< 92.2 proven).
    //  A [0,        4718592)  xd NHWC bf16 (deform->sa_scale);
    //                         then tn1 bf16 [0,2359296) + tn2 bf16 [2359296,4718592).
    //  B [4718592,  9437184)  xa NHWC bf16 (sa_scale -> r1 x2, n1).
    //  C [9437184, 11427840)  om bf16 (off -> deform).
    //  D [11427840,11553536)  ca_part, ca_o, prepacked weights.
    //  E [11553536,20990720)  x NHWC bf16 (first 4718592 f; dead after deform)
    //                         -> tr 2-batch bf16 (full 9437184 f).
    // ------------------------------------------------------------------
    float* ws = (float*)d_ws;
    unsigned short* xd_bhwc = (unsigned short*)ws;                    // A
    unsigned short* tn1     = (unsigned short*)ws;                    // A (late)
    unsigned short* tn2     = (unsigned short*)(ws + 2359296);        // A (late)
    unsigned short* xa_bhwc = (unsigned short*)(ws + 4718592);        // B
    unsigned short* om      = (unsigned short*)(ws + 9437184);        // C: 3981312 sh
    float* ca_part = ws + 11427840;                                   // 9216 f
    float* ca_o    = ws + 11437056;                                   // 256 f
    unsigned short* Apk1  = (unsigned short*)(ws + 11437312);         // 16384 sh
    unsigned short* Apk2  = Apk1 + 16384;                             // 147456 sh
    unsigned short* Wofpk = Apk2 + 147456;                            // 18432 sh
    unsigned short* Wdcb  = Wofpk + 18432;                            // 36864 sh
    unsigned short* Wsapk = Wdcb + 36864;                             // 9216 sh
    unsigned short* Wn1pk = Wsapk + 9216;                             // 2048 sh
    unsigned short* Wn3pk = Wn1pk + 2048;                             // 2048 sh
    unsigned short* x_bhwc = (unsigned short*)(ws + 11553536);        // E (early)
    unsigned short* trh    = (unsigned short*)(ws + 11553536);        // E (after deform)

    k_x_t        <<<dim3(HW / 64, 4), 256, 0, stream>>>(x, x_bhwc);
    k_prepack    <<<908, 256, 0, stream>>>(w_r1, w_r2, w_off, w_dc, w_sa, w_n1, w_n3,
                                           Apk1, Apk2, Wofpk, Wdcb, Wsapk, Wn1pk, Wn3pk);
    k_off_mfma   <<<dim3(3, 192, 4), 256, 0, stream>>>(x_bhwc, Wofpk, b_off, om);
    k_deform_mfma<<<dim3(576, 4), 256, 0, stream>>>(x_bhwc, om, Wdcb, b_dc, xd_bhwc);
    k_camean     <<<dim3(36, 4), 256, 0, stream>>>(xd_bhwc, ca_part);
    k_ca_mlp     <<<1, 256, 0, stream>>>(ca_part, w_ca1, b_ca1, w_ca2, b_ca2, ca_o);
    k_sa_scale   <<<dim3(3, 192, 4), 256, 0, stream>>>(xd_bhwc, Wsapk, b_sa, ca_o, xa_bhwc);

    // r-branch: two 2-batch slabs through tr (stream-serialized)
    for (int s = 0; s < 2; ++s) {
        k_r1_mfma<<<(2 * HW) / 64, 256, 0, stream>>>(xa_bhwc + (size_t)s * 2 * HW * 64,
                                                     Apk1, b_r1, trh);
        k_r2_mfma<<<dim3(2, 192, 2), 256, 0, stream>>>(trh, Apk2, b_r2, out, s * 2);
    }

    // n-branch (NHWC bf16 throughout)
    k_n1_mfma   <<<dim3(576, 4), 256, 0, stream>>>(xa_bhwc, Wn1pk, b_n1, tn1);
    k_dw3x3     <<<dim3(3, 192, 4), 256, 0, stream>>>(tn1, w_n2, b_n2, tn2);
    k_final_mfma<<<dim3(576, 4), 256, 0, stream>>>(x, tn2, Wn3pk, b_n3, out);
}